// Round 11
// baseline (866.051 us; speedup 1.0000x reference)
//
#include <hip/hip_runtime.h>
#include <cstdint>
#include <cstddef>

#define NN 100000
#define NE 1600000
#define NTOT (NE + NN)      // 1700000 edges incl self-loops
#define HF 128
#define OF 64
#define SHARD 12500         // NN/8 dst-range per XCD
#define EPB 1924            // edges per chunk: 832*1924 >= NE
#define NPB 16              // shard nodes per chunk: 832*16 >= SHARD

typedef short bfrag_t __attribute__((ext_vector_type(8)));   // 8 bf16 = 4 VGPR
typedef float f4v     __attribute__((ext_vector_type(4)));   // MFMA acc

// ---------------- helpers ----------------

__device__ __forceinline__ unsigned int f2bf_rne(float f) {
    unsigned int u = __float_as_uint(f);
    return (u + 0x7fffu + ((u >> 16) & 1u)) >> 16;
}
__device__ __forceinline__ unsigned int pack_bf2(float lo, float hi) {
    return f2bf_rne(lo) | (f2bf_rne(hi) << 16);
}

// ---------------- graph preprocessing ----------------

__global__ __launch_bounds__(256) void k_init(int* flag, int* deg) {
    int i = blockIdx.x * 256 + threadIdx.x;
    if (i == 0) *flag = 0;
    if (i < NN) deg[i] = 1;   // self-loop
}

__global__ __launch_bounds__(256) void k_detect(const int* ei, int* flag) {
    int t = blockIdx.x * blockDim.x + threadIdx.x;
    int v = 0;
    for (int i = t; i < NE; i += gridDim.x * blockDim.x) v |= ei[2 * i + 1];
    unsigned long long b = __ballot(v != 0);
    if ((threadIdx.x & 63) == 0 && b) atomicOr(flag, 1);
}

__device__ __forceinline__ int edge_src(const int* ei, int e, bool is64) {
    return is64 ? ei[2 * e] : ei[e];
}
__device__ __forceinline__ int edge_dst(const int* ei, int e, bool is64) {
    return is64 ? ei[2 * (NE + e)] : ei[NE + e];
}

// XCD-sharded histogram: deg lines each touched by ONE XCD -> local atomics.
__global__ __launch_bounds__(256) void k_hist8(const int* __restrict__ ei,
                                               const int* __restrict__ flag,
                                               int* __restrict__ deg) {
    int x = blockIdx.x & 7, c = blockIdx.x >> 3;
    bool is64 = (*flag) == 0;
    int d0 = x * SHARD;
    int ebeg = c * EPB;
    int eend = min(NE, ebeg + EPB);
    for (int e = ebeg + (int)threadIdx.x; e < eend; e += 256) {
        int d = edge_dst(ei, e, is64);
        if ((unsigned)(d - d0) < SHARD) atomicAdd(&deg[d], 1);
    }
}

// exclusive scan of deg[N] -> rowptr (partial), also dinv = rsqrt(deg)
__global__ __launch_bounds__(256) void k_scanA(const int* deg, int* rowptr, int* bsum,
                                               float* dinv) {
    __shared__ int sh[256];
    int tid = threadIdx.x;
    int base = blockIdx.x * 1024 + tid * 4;
    int v0 = 0, v1 = 0, v2 = 0, v3 = 0;
    if (base + 0 < NN) v0 = deg[base + 0];
    if (base + 1 < NN) v1 = deg[base + 1];
    if (base + 2 < NN) v2 = deg[base + 2];
    if (base + 3 < NN) v3 = deg[base + 3];
    if (base + 0 < NN) dinv[base + 0] = rsqrtf((float)v0);
    if (base + 1 < NN) dinv[base + 1] = rsqrtf((float)v1);
    if (base + 2 < NN) dinv[base + 2] = rsqrtf((float)v2);
    if (base + 3 < NN) dinv[base + 3] = rsqrtf((float)v3);
    int s = v0 + v1 + v2 + v3;
    sh[tid] = s;
    __syncthreads();
    for (int off = 1; off < 256; off <<= 1) {
        int t = (tid >= off) ? sh[tid - off] : 0;
        __syncthreads();
        sh[tid] += t;
        __syncthreads();
    }
    int run = sh[tid] - s;
    if (base + 0 < NN) rowptr[base + 0] = run; run += v0;
    if (base + 1 < NN) rowptr[base + 1] = run; run += v1;
    if (base + 2 < NN) rowptr[base + 2] = run; run += v2;
    if (base + 3 < NN) rowptr[base + 3] = run;
    if (tid == 255) bsum[blockIdx.x] = sh[255];
}

__global__ __launch_bounds__(128) void k_scanB(const int* bsum, int* boff, int* rowptr) {
    __shared__ int sh[128];
    int tid = threadIdx.x;
    int v = (tid < 98) ? bsum[tid] : 0;
    sh[tid] = v;
    __syncthreads();
    for (int off = 1; off < 128; off <<= 1) {
        int t = (tid >= off) ? sh[tid - off] : 0;
        __syncthreads();
        sh[tid] += t;
        __syncthreads();
    }
    if (tid < 98) boff[tid] = sh[tid] - v;
    if (tid == 0) rowptr[NN] = NTOT;
}

__global__ __launch_bounds__(256) void k_scanC(int* rowptr, const int* boff, int* cursor) {
    int i = blockIdx.x * 256 + threadIdx.x;
    if (i < NN) {
        int r = rowptr[i] + boff[i >> 10];
        rowptr[i] = r;
        cursor[i] = r + 1;   // slot r reserved for the self-loop
    }
}

// XCD-sharded CSR fill with shard-local atomic cursor.
__global__ __launch_bounds__(256) void k_scat3(const int* __restrict__ ei,
                                               const int* __restrict__ flag,
                                               int* __restrict__ cursor,
                                               const int* __restrict__ rowptr,
                                               int* __restrict__ csr) {
    int x = blockIdx.x & 7, c = blockIdx.x >> 3;
    bool is64 = (*flag) == 0;
    int d0 = x * SHARD;
    int nbeg = d0 + c * NPB;
    int nend = min(d0 + SHARD, nbeg + NPB);
    for (int nd = nbeg + (int)threadIdx.x; nd < nend; nd += 256)
        csr[rowptr[nd]] = nd;                       // self-loop slot
    int ebeg = c * EPB;
    int eend = min(NE, ebeg + EPB);
    for (int e = ebeg + (int)threadIdx.x; e < eend; e += 256) {
        int d = edge_dst(ei, e, is64);
        if ((unsigned)(d - d0) < SHARD) {
            int s = edge_src(ei, e, is64);
            int pos = atomicAdd(&cursor[d], 1);
            csr[pos] = s;
        }
    }
}

// ---------------- x -> bf16, pre-scaled by dinv (gather source) ----------------
__global__ __launch_bounds__(256) void k_xcvt2(const float* __restrict__ x,
                                               const float* __restrict__ dinv,
                                               unsigned int* __restrict__ out4) {
    int i = blockIdx.x * 256 + threadIdx.x;      // one uint4 (8 bf16) per thread
    if (i >= NN * 16) return;
    float dv = dinv[i >> 4];
    float4 v0 = ((const float4*)x)[(size_t)i * 2];
    float4 v1 = ((const float4*)x)[(size_t)i * 2 + 1];
    uint4 o;
    o.x = pack_bf2(v0.x * dv, v0.y * dv);
    o.y = pack_bf2(v0.z * dv, v0.w * dv);
    o.z = pack_bf2(v1.x * dv, v1.y * dv);
    o.w = pack_bf2(v1.z * dv, v1.w * dv);
    ((uint4*)out4)[i] = o;
}

// ---------------- weight prep: bf16 + transpose to [n][k] ----------------
__global__ __launch_bounds__(256) void k_prep(const float* __restrict__ W0,
                                              const float* __restrict__ W1,
                                              const float* __restrict__ W2,
                                              const float* __restrict__ W3,
                                              const float* __restrict__ linW,
                                              unsigned short* __restrict__ WT,
                                              unsigned short* __restrict__ WjT) {
    int idx = blockIdx.x * 256 + threadIdx.x;
    if (idx < 4 * 128 * 128) {
        int l = idx >> 14, r = idx & 16383, n = r >> 7, k = r & 127;
        const float* Wl = (l == 0) ? W0 : (l == 1) ? W1 : (l == 2) ? W2 : W3;
        WT[idx] = (unsigned short)f2bf_rne(Wl[k * 128 + n]);
    } else if (idx < 4 * 128 * 128 + 4 * 64 * 128) {
        int i2 = idx - 65536;
        int l = i2 >> 13, r = i2 & 8191, n = r >> 7, k = r & 127;
        WjT[i2] = (unsigned short)f2bf_rne(linW[(size_t)(l * 128 + k) * 64 + n]);
    }
}

// ---------------- fused layer: gather+sum -> MFMA(W) -> relu -> MFMA(JK) ----------------
// Uses linearity: h'_d = relu(dinv_d * (sum_s dinv_s h_s) @ W + b); input hs is
// bf16 dinv-pre-scaled h. This layer's OWN jk (logits += h' @ Wjk) is computed
// via an LDS round-trip of h'. Output hs_out = bf16(dinv*h') for the next layer.
__global__ __launch_bounds__(256) void k_layer(const int* __restrict__ rowptr,
                                               const int* __restrict__ csr,
                                               const uint4* __restrict__ hs4,
                                               const unsigned short* __restrict__ WT,
                                               const unsigned short* __restrict__ WjT,
                                               const float* __restrict__ dinv,
                                               const float* __restrict__ bias,
                                               const float* __restrict__ linb,
                                               float* __restrict__ logits,
                                               int first, int last,
                                               unsigned short* __restrict__ hs_out) {
    __shared__ unsigned short Wlds[128 * 128];   // 32 KB, swizzled
    __shared__ unsigned short Wjlds[64 * 128];   // 16 KB, swizzled
    __shared__ unsigned short Asum[64 * 128];    // 16 KB, swizzled; reused for h'
    int tid = threadIdx.x;
    int row0 = blockIdx.x * 64;

    for (int c = tid; c < 2048; c += 256) {       // stage W^T
        int row = c >> 4, c16 = c & 15;
        uint4 v = *(const uint4*)&WT[row * 128 + c16 * 8];
        *(uint4*)((char*)Wlds + row * 256 + ((c16 * 16) ^ ((row & 7) << 4))) = v;
    }
    for (int c = tid; c < 1024; c += 256) {       // stage Wjk^T
        int row = c >> 4, c16 = c & 15;
        uint4 v = *(const uint4*)&WjT[row * 128 + c16 * 8];
        *(uint4*)((char*)Wjlds + row * 256 + ((c16 * 16) ^ ((row & 7) << 4))) = v;
    }

    // ---- gather+sum phase (k_agg inner structure); wave w -> rows 16w..16w+15
    int lane = tid & 63, w = tid >> 6;
    int grp = lane >> 4, lj = lane & 15;
    for (int i = 0; i < 16; ++i) {
        int row = 16 * w + i;
        int node = min(row0 + row, NN - 1);       // clamp: OOB rows do dummy work
        int beg = rowptr[node], end = rowptr[node + 1];
        float a[8];
#pragma unroll
        for (int q = 0; q < 8; ++q) a[q] = 0.f;
        auto acc8 = [&](uint4 v) {
            a[0] += __uint_as_float(v.x << 16);
            a[1] += __uint_as_float(v.x & 0xffff0000u);
            a[2] += __uint_as_float(v.y << 16);
            a[3] += __uint_as_float(v.y & 0xffff0000u);
            a[4] += __uint_as_float(v.z << 16);
            a[5] += __uint_as_float(v.z & 0xffff0000u);
            a[6] += __uint_as_float(v.w << 16);
            a[7] += __uint_as_float(v.w & 0xffff0000u);
        };
        for (int base = beg; base < end; base += 64) {
            int cnt = min(64, end - base);
            int sv = (lane < cnt) ? csr[base + lane] : 0;
            int k = 0;
            for (; k + 16 <= cnt; k += 16) {
                int s0 = __shfl(sv, k + grp);
                int s1 = __shfl(sv, k + 4 + grp);
                int s2 = __shfl(sv, k + 8 + grp);
                int s3 = __shfl(sv, k + 12 + grp);
                uint4 v0 = hs4[(size_t)s0 * 16 + lj];
                uint4 v1 = hs4[(size_t)s1 * 16 + lj];
                uint4 v2 = hs4[(size_t)s2 * 16 + lj];
                uint4 v3 = hs4[(size_t)s3 * 16 + lj];
                acc8(v0); acc8(v1); acc8(v2); acc8(v3);
            }
            for (; k + 4 <= cnt; k += 4) {        // wave-uniform
                int s = __shfl(sv, k + grp);
                acc8(hs4[(size_t)s * 16 + lj]);
            }
            int rem = cnt - k;                    // 0..3
            if (rem) {                            // wave-uniform
                int idx = k + grp;
                if (idx >= cnt) idx = cnt - 1;    // clamp; shuffle by ALL lanes
                int s = __shfl(sv, idx);
                if (grp < rem) acc8(hs4[(size_t)s * 16 + lj]);
            }
        }
#pragma unroll
        for (int q = 0; q < 8; ++q) a[q] += __shfl_xor(a[q], 16);
#pragma unroll
        for (int q = 0; q < 8; ++q) a[q] += __shfl_xor(a[q], 32);
        if (grp == 0) {                           // raw sum -> bf16 (no dinv/bias)
            uint4 o;
            o.x = pack_bf2(a[0], a[1]);
            o.y = pack_bf2(a[2], a[3]);
            o.z = pack_bf2(a[4], a[5]);
            o.w = pack_bf2(a[6], a[7]);
            *(uint4*)((char*)Asum + row * 256 + ((lj * 16) ^ ((row & 7) << 4))) = o;
        }
    }
    __syncthreads();   // B1: W/Wjk staged + Asum complete

    int r15 = lane & 15, q = lane >> 4;
    int xo = (r15 & 7) << 4;
    bfrag_t afr[4];
#pragma unroll
    for (int ks = 0; ks < 4; ++ks)
        afr[ks] = *(const bfrag_t*)((const char*)Asum + (16 * w + r15) * 256
                                    + ((ks * 64 + q * 16) ^ xo));
    __syncthreads();   // B2: all Asum reads done (buffer will be overwritten)

    f4v acc[8];
#pragma unroll
    for (int i = 0; i < 8; ++i) acc[i] = (f4v){0.f, 0.f, 0.f, 0.f};
#pragma unroll
    for (int ks = 0; ks < 4; ++ks) {
        int ko = ks * 64 + q * 16;
#pragma unroll
        for (int nb = 0; nb < 8; ++nb) {
            bfrag_t b = *(const bfrag_t*)((const char*)Wlds + (nb * 16 + r15) * 256 + (ko ^ xo));
            acc[nb] = __builtin_amdgcn_mfma_f32_16x16x32_bf16(afr[ks], b, acc[nb], 0, 0, 0);
        }
    }

    // epilogue: h' = relu(dinv*acc + b); write hs_out; stash h' bf16 into Asum
#pragma unroll
    for (int reg = 0; reg < 4; ++reg) {
        int crow = q * 4 + reg;                   // C row within wave tile
        int lrow = 16 * w + crow;                 // local row in block
        int gr = row0 + lrow;
        bool valid = gr < NN;
        float dv = dinv[min(gr, NN - 1)];
#pragma unroll
        for (int nb = 0; nb < 8; ++nb) {
            int col = nb * 16 + r15;
            float h = fmaxf(acc[nb][reg] * dv + bias[col], 0.f);
            unsigned short hb = (unsigned short)f2bf_rne(h);
            *(unsigned short*)((char*)Asum + lrow * 256 + (((unsigned)(col * 2)) ^ ((lrow & 7) << 4))) = hb;
            if (valid && !last)
                hs_out[(size_t)gr * 128 + col] = (unsigned short)f2bf_rne(h * dv);
        }
    }
    __syncthreads();   // B3: h' stash complete

    bfrag_t jfr[4];
#pragma unroll
    for (int ks = 0; ks < 4; ++ks)
        jfr[ks] = *(const bfrag_t*)((const char*)Asum + (16 * w + r15) * 256
                                    + ((ks * 64 + q * 16) ^ xo));
    f4v accj[4];
#pragma unroll
    for (int i = 0; i < 4; ++i) accj[i] = (f4v){0.f, 0.f, 0.f, 0.f};
#pragma unroll
    for (int ks = 0; ks < 4; ++ks) {
        int ko = ks * 64 + q * 16;
#pragma unroll
        for (int jb = 0; jb < 4; ++jb) {
            bfrag_t b = *(const bfrag_t*)((const char*)Wjlds + (jb * 16 + r15) * 256 + (ko ^ xo));
            accj[jb] = __builtin_amdgcn_mfma_f32_16x16x32_bf16(jfr[ks], b, accj[jb], 0, 0, 0);
        }
    }
#pragma unroll
    for (int reg = 0; reg < 4; ++reg) {
        int gr = row0 + 16 * w + q * 4 + reg;
        if (gr < NN) {
#pragma unroll
            for (int jb = 0; jb < 4; ++jb) {
                size_t off = (size_t)gr * 64 + jb * 16 + r15;
                float prev = first ? linb[jb * 16 + r15] : logits[off];
                logits[off] = prev + accj[jb][reg];
            }
        }
    }
}

// in-place log_softmax over rows of 64; one wave per row
__global__ __launch_bounds__(256) void k_lsm(float* __restrict__ logits) {
    int w = threadIdx.x >> 6, lane = threadIdx.x & 63;
    int r = blockIdx.x * 4 + w;
    if (r >= NN) return;
    float v = logits[(size_t)r * 64 + lane];
    float m = v;
#pragma unroll
    for (int off = 32; off; off >>= 1) m = fmaxf(m, __shfl_xor(m, off));
    float e = expf(v - m);
    float s = e;
#pragma unroll
    for (int off = 32; off; off >>= 1) s += __shfl_xor(s, off);
    logits[(size_t)r * 64 + lane] = v - m - logf(s);
}

// ---------------- launch ----------------

extern "C" void kernel_launch(void* const* d_in, const int* in_sizes, int n_in,
                              void* d_out, int out_size, void* d_ws, size_t ws_size,
                              hipStream_t stream) {
    const float* x    = (const float*)d_in[0];
    const int*   ei   = (const int*)d_in[1];
    const float* W[4] = {(const float*)d_in[2], (const float*)d_in[4],
                         (const float*)d_in[6], (const float*)d_in[8]};
    const float* b[4] = {(const float*)d_in[3], (const float*)d_in[5],
                         (const float*)d_in[7], (const float*)d_in[9]};
    const float* linW = (const float*)d_in[10];
    const float* linb = (const float*)d_in[11];
    float* out = (float*)d_out;

    char* wp = (char*)d_ws;
    auto alloc = [&](size_t bytes) {
        void* p = (void*)wp;
        wp += (bytes + 255) & ~(size_t)255;
        return p;
    };
    int*   flag   = (int*)  alloc(4);
    int*   deg    = (int*)  alloc((size_t)NN * 4);
    float* dinv   = (float*)alloc((size_t)NN * 4);
    int*   rowptr = (int*)  alloc((size_t)(NN + 1) * 4);
    int*   cursor = (int*)  alloc((size_t)NN * 4);
    int*   bsum   = (int*)  alloc(512);
    int*   boff   = (int*)  alloc(512);
    int*   csr    = (int*)  alloc((size_t)NTOT * 4);
    unsigned short* WT  = (unsigned short*)alloc((size_t)4 * 128 * 128 * 2);
    unsigned short* WjT = (unsigned short*)alloc((size_t)4 * 64 * 128 * 2);
    unsigned short* xs   = (unsigned short*)alloc((size_t)NN * 128 * 2); // dinv*x bf16
    unsigned short* hsA  = (unsigned short*)alloc((size_t)NN * 128 * 2); // dinv*h bf16
    unsigned short* hsB  = (unsigned short*)alloc((size_t)NN * 128 * 2);

    dim3 blk(256);
    k_init   <<<391, blk, 0, stream>>>(flag, deg);
    k_prep   <<<384, blk, 0, stream>>>(W[0], W[1], W[2], W[3], linW, WT, WjT);
    k_detect <<<1024, blk, 0, stream>>>(ei, flag);
    k_hist8  <<<6656, blk, 0, stream>>>(ei, flag, deg);
    k_scanA  <<<98, blk, 0, stream>>>(deg, rowptr, bsum, dinv);
    k_scanB  <<<1, dim3(128), 0, stream>>>(bsum, boff, rowptr);
    k_scanC  <<<391, blk, 0, stream>>>(rowptr, boff, cursor);
    k_xcvt2  <<<6250, blk, 0, stream>>>(x, dinv, (unsigned int*)xs);
    k_scat3  <<<6656, blk, 0, stream>>>(ei, flag, cursor, rowptr, csr);

    const unsigned short* lin[4] = {xs, hsA, hsB, hsA};
    unsigned short*      lout[4] = {hsA, hsB, hsA, hsB};
    for (int l = 0; l < 4; ++l) {
        k_layer<<<1563, blk, 0, stream>>>(rowptr, csr, (const uint4*)lin[l],
                                          WT + (size_t)l * 128 * 128,
                                          WjT + (size_t)l * 64 * 128,
                                          dinv, b[l], linb, out,
                                          l == 0 ? 1 : 0, l == 3 ? 1 : 0, lout[l]);
    }
    k_lsm<<<25000, blk, 0, stream>>>(out);
}

// Round 12
// 595.455 us; speedup vs baseline: 1.4544x; 1.4544x over previous
//
#include <hip/hip_runtime.h>
#include <cstdint>
#include <cstddef>

#define NN 100000
#define NE 1600000
#define NTOT (NE + NN)      // 1700000 edges incl self-loops
#define HF 128
#define OF 64
#define SHARD 12500         // NN/8 dst-range per XCD
#define EPB 1924            // edges per chunk: 832*1924 >= NE
#define NPB 16              // shard nodes per chunk: 832*16 >= SHARD

typedef short bfrag_t __attribute__((ext_vector_type(8)));   // 8 bf16 = 4 VGPR
typedef float f4v     __attribute__((ext_vector_type(4)));   // MFMA acc

// ---------------- helpers ----------------

__device__ __forceinline__ unsigned int f2bf_rne(float f) {
    unsigned int u = __float_as_uint(f);
    return (u + 0x7fffu + ((u >> 16) & 1u)) >> 16;
}
__device__ __forceinline__ unsigned int pack_bf2(float lo, float hi) {
    return f2bf_rne(lo) | (f2bf_rne(hi) << 16);
}

// ---------------- graph preprocessing ----------------

__global__ __launch_bounds__(256) void k_init(int* flag, int* deg) {
    int i = blockIdx.x * 256 + threadIdx.x;
    if (i == 0) *flag = 0;
    if (i < NN) deg[i] = 1;   // self-loop
}

// OR-reduce odd 32-bit words of edge_index: all zero <=> data is int64.
__global__ __launch_bounds__(256) void k_detect(const int* ei, int* flag) {
    int t = blockIdx.x * blockDim.x + threadIdx.x;
    int v = 0;
    for (int i = t; i < NE; i += gridDim.x * blockDim.x)
        v |= __builtin_nontemporal_load(&ei[2 * i + 1]);
    unsigned long long b = __ballot(v != 0);
    if ((threadIdx.x & 63) == 0 && b) atomicOr(flag, 1);
}

__device__ __forceinline__ int edge_src_nt(const int* ei, int e, bool is64) {
    return is64 ? __builtin_nontemporal_load(&ei[2 * e])
                : __builtin_nontemporal_load(&ei[e]);
}
__device__ __forceinline__ int edge_dst_nt(const int* ei, int e, bool is64) {
    return is64 ? __builtin_nontemporal_load(&ei[2 * (NE + e)])
                : __builtin_nontemporal_load(&ei[NE + e]);
}

// XCD-sharded histogram: deg lines each touched by ONE XCD -> local atomics.
// ei streamed with NT loads so it doesn't evict the hot deg lines.
__global__ __launch_bounds__(256) void k_hist8(const int* __restrict__ ei,
                                               const int* __restrict__ flag,
                                               int* __restrict__ deg) {
    int x = blockIdx.x & 7, c = blockIdx.x >> 3;
    bool is64 = (*flag) == 0;
    int d0 = x * SHARD;
    int ebeg = c * EPB;
    int eend = min(NE, ebeg + EPB);
    for (int e = ebeg + (int)threadIdx.x; e < eend; e += 256) {
        int d = edge_dst_nt(ei, e, is64);
        if ((unsigned)(d - d0) < SHARD) atomicAdd(&deg[d], 1);
    }
}

// exclusive scan of deg[N] -> rowptr (partial), also dinv = rsqrt(deg)
__global__ __launch_bounds__(256) void k_scanA(const int* deg, int* rowptr, int* bsum,
                                               float* dinv) {
    __shared__ int sh[256];
    int tid = threadIdx.x;
    int base = blockIdx.x * 1024 + tid * 4;
    int v0 = 0, v1 = 0, v2 = 0, v3 = 0;
    if (base + 0 < NN) v0 = deg[base + 0];
    if (base + 1 < NN) v1 = deg[base + 1];
    if (base + 2 < NN) v2 = deg[base + 2];
    if (base + 3 < NN) v3 = deg[base + 3];
    if (base + 0 < NN) dinv[base + 0] = rsqrtf((float)v0);
    if (base + 1 < NN) dinv[base + 1] = rsqrtf((float)v1);
    if (base + 2 < NN) dinv[base + 2] = rsqrtf((float)v2);
    if (base + 3 < NN) dinv[base + 3] = rsqrtf((float)v3);
    int s = v0 + v1 + v2 + v3;
    sh[tid] = s;
    __syncthreads();
    for (int off = 1; off < 256; off <<= 1) {
        int t = (tid >= off) ? sh[tid - off] : 0;
        __syncthreads();
        sh[tid] += t;
        __syncthreads();
    }
    int run = sh[tid] - s;
    if (base + 0 < NN) rowptr[base + 0] = run; run += v0;
    if (base + 1 < NN) rowptr[base + 1] = run; run += v1;
    if (base + 2 < NN) rowptr[base + 2] = run; run += v2;
    if (base + 3 < NN) rowptr[base + 3] = run;
    if (tid == 255) bsum[blockIdx.x] = sh[255];
}

__global__ __launch_bounds__(128) void k_scanB(const int* bsum, int* boff, int* rowptr) {
    __shared__ int sh[128];
    int tid = threadIdx.x;
    int v = (tid < 98) ? bsum[tid] : 0;
    sh[tid] = v;
    __syncthreads();
    for (int off = 1; off < 128; off <<= 1) {
        int t = (tid >= off) ? sh[tid - off] : 0;
        __syncthreads();
        sh[tid] += t;
        __syncthreads();
    }
    if (tid < 98) boff[tid] = sh[tid] - v;
    if (tid == 0) rowptr[NN] = NTOT;
}

__global__ __launch_bounds__(256) void k_scanC(int* rowptr, const int* boff, int* cursor) {
    int i = blockIdx.x * 256 + threadIdx.x;
    if (i < NN) {
        int r = rowptr[i] + boff[i >> 10];
        rowptr[i] = r;
        cursor[i] = r + 1;   // slot r reserved for the self-loop
    }
}

// XCD-sharded CSR fill with shard-local atomic cursor; ei via NT loads so the
// stream doesn't evict the hot cursor/csr lines from the local L2.
__global__ __launch_bounds__(256) void k_scat3(const int* __restrict__ ei,
                                               const int* __restrict__ flag,
                                               int* __restrict__ cursor,
                                               const int* __restrict__ rowptr,
                                               int* __restrict__ csr) {
    int x = blockIdx.x & 7, c = blockIdx.x >> 3;
    bool is64 = (*flag) == 0;
    int d0 = x * SHARD;
    int nbeg = d0 + c * NPB;
    int nend = min(d0 + SHARD, nbeg + NPB);
    for (int nd = nbeg + (int)threadIdx.x; nd < nend; nd += 256)
        csr[rowptr[nd]] = nd;                       // self-loop slot
    int ebeg = c * EPB;
    int eend = min(NE, ebeg + EPB);
    for (int e = ebeg + (int)threadIdx.x; e < eend; e += 256) {
        int d = edge_dst_nt(ei, e, is64);
        if ((unsigned)(d - d0) < SHARD) {
            int s = edge_src_nt(ei, e, is64);
            int pos = atomicAdd(&cursor[d], 1);
            csr[pos] = s;
        }
    }
}

// ---------------- x f32 -> bf16 ----------------
__global__ __launch_bounds__(256) void k_xcvt(const float* __restrict__ x,
                                              unsigned int* __restrict__ xb4) {
    int i = blockIdx.x * 256 + threadIdx.x;      // one uint4 (8 bf16) per thread
    if (i >= NN * 16) return;
    float4 v0 = ((const float4*)x)[(size_t)i * 2];
    float4 v1 = ((const float4*)x)[(size_t)i * 2 + 1];
    uint4 o;
    o.x = pack_bf2(v0.x, v0.y);
    o.y = pack_bf2(v0.z, v0.w);
    o.z = pack_bf2(v1.x, v1.y);
    o.w = pack_bf2(v1.z, v1.w);
    ((uint4*)xb4)[i] = o;
}

// ---------------- weight prep: bf16 + transpose to [n][k] ----------------
__global__ __launch_bounds__(256) void k_prep(const float* __restrict__ W0,
                                              const float* __restrict__ W1,
                                              const float* __restrict__ W2,
                                              const float* __restrict__ W3,
                                              const float* __restrict__ linW,
                                              unsigned short* __restrict__ WT,
                                              unsigned short* __restrict__ WjT) {
    int idx = blockIdx.x * 256 + threadIdx.x;
    if (idx < 4 * 128 * 128) {
        int l = idx >> 14, r = idx & 16383, n = r >> 7, k = r & 127;
        const float* Wl = (l == 0) ? W0 : (l == 1) ? W1 : (l == 2) ? W2 : W3;
        WT[idx] = (unsigned short)f2bf_rne(Wl[k * 128 + n]);
    } else if (idx < 4 * 128 * 128 + 4 * 64 * 128) {
        int i2 = idx - 65536;
        int l = i2 >> 13, r = i2 & 8191, n = r >> 7, k = r & 127;
        WjT[i2] = (unsigned short)f2bf_rne(linW[(size_t)(l * 128 + k) * 64 + n]);
    }
}

// ---------------- MFMA matmul + fused JK ----------------
// A is bf16 [N][128]; A fragments loaded DIRECTLY from global (contiguous 16 B
// per lane: row*256B + ks*64B + q*16B) -> no A-LDS stage, one barrier.
__global__ __launch_bounds__(256) void k_mmf(const unsigned short* __restrict__ A,
                                             const unsigned short* __restrict__ WT,
                                             const float* __restrict__ dinv,
                                             const unsigned short* __restrict__ WjT,
                                             const float* __restrict__ linb,
                                             float* __restrict__ logits, int first,
                                             unsigned short* __restrict__ m16) {
    __shared__ unsigned short Wlds[128 * 128];   // 32 KB
    __shared__ unsigned short Wjlds[64 * 128];   // 16 KB
    int tid = threadIdx.x;
    int row0 = blockIdx.x * 64;
    bool has_jk = (WjT != nullptr);

    for (int c = tid; c < 2048; c += 256) {       // W^T, swizzled
        int row = c >> 4, c16 = c & 15;
        uint4 v = *(const uint4*)&WT[row * 128 + c16 * 8];
        *(uint4*)((char*)Wlds + row * 256 + ((c16 * 16) ^ ((row & 7) << 4))) = v;
    }
    if (has_jk) {
        for (int c = tid; c < 1024; c += 256) {
            int row = c >> 4, c16 = c & 15;
            uint4 v = *(const uint4*)&WjT[row * 128 + c16 * 8];
            *(uint4*)((char*)Wjlds + row * 256 + ((c16 * 16) ^ ((row & 7) << 4))) = v;
        }
    }

    int lane = tid & 63, w = tid >> 6;
    int r15 = lane & 15, q = lane >> 4;
    int xo = (r15 & 7) << 4;

    int arow = row0 + 16 * w + r15;
    bool av = arow < NN;
    bfrag_t afr[4];
#pragma unroll
    for (int ks = 0; ks < 4; ++ks) {
        bfrag_t z = {0, 0, 0, 0, 0, 0, 0, 0};
        afr[ks] = av ? *(const bfrag_t*)&A[(size_t)arow * 128 + ks * 32 + q * 8] : z;
    }
    __syncthreads();

    f4v acc[8], accj[4];
#pragma unroll
    for (int i = 0; i < 8; ++i) acc[i] = (f4v){0.f, 0.f, 0.f, 0.f};
#pragma unroll
    for (int i = 0; i < 4; ++i) accj[i] = (f4v){0.f, 0.f, 0.f, 0.f};

#pragma unroll
    for (int ks = 0; ks < 4; ++ks) {
        int ko = ks * 64 + q * 16;
        bfrag_t a = afr[ks];
#pragma unroll
        for (int nb = 0; nb < 8; ++nb) {
            bfrag_t b = *(const bfrag_t*)((const char*)Wlds + (nb * 16 + r15) * 256 + (ko ^ xo));
            acc[nb] = __builtin_amdgcn_mfma_f32_16x16x32_bf16(a, b, acc[nb], 0, 0, 0);
        }
        if (has_jk) {
#pragma unroll
            for (int jb = 0; jb < 4; ++jb) {
                bfrag_t b = *(const bfrag_t*)((const char*)Wjlds + (jb * 16 + r15) * 256 + (ko ^ xo));
                accj[jb] = __builtin_amdgcn_mfma_f32_16x16x32_bf16(a, b, accj[jb], 0, 0, 0);
            }
        }
    }

#pragma unroll
    for (int reg = 0; reg < 4; ++reg) {
        int gr = row0 + 16 * w + q * 4 + reg;
        if (gr < NN) {
            float sc = dinv[gr];
#pragma unroll
            for (int nb = 0; nb < 8; ++nb)
                m16[(size_t)gr * 128 + nb * 16 + r15] =
                    (unsigned short)f2bf_rne(acc[nb][reg] * sc);
            if (has_jk) {
#pragma unroll
                for (int jb = 0; jb < 4; ++jb) {
                    size_t off = (size_t)gr * 64 + jb * 16 + r15;
                    float prev = first ? linb[jb * 16 + r15] : logits[off];
                    logits[off] = prev + accj[jb][reg];
                }
            }
        }
    }
}

// h_out[d][:] = bf16(relu(dinv[d] * sum_{s in N(d)} bf16m[s][:] + b))
// one wave per node; 4 groups of 16 lanes gather full 256 B rows (16 B/lane);
// 16-edge inner step = 4 independent gathers in flight. csr via NT loads
// (streamed once -> don't evict reused m rows from L2).
__global__ __launch_bounds__(256) void k_agg(const int* __restrict__ rowptr,
                                             const int* __restrict__ csr,
                                             const uint4* __restrict__ m4,
                                             const float* __restrict__ dinv,
                                             const float* __restrict__ bias,
                                             unsigned short* __restrict__ outb) {
    int w = threadIdx.x >> 6, lane = threadIdx.x & 63;
    int grp = lane >> 4, lj = lane & 15;
    int node = blockIdx.x * 4 + w;
    if (node >= NN) return;
    int beg = rowptr[node], end = rowptr[node + 1];

    float a[8];
#pragma unroll
    for (int q = 0; q < 8; ++q) a[q] = 0.f;

    auto acc8 = [&](uint4 v) {
        a[0] += __uint_as_float(v.x << 16);
        a[1] += __uint_as_float(v.x & 0xffff0000u);
        a[2] += __uint_as_float(v.y << 16);
        a[3] += __uint_as_float(v.y & 0xffff0000u);
        a[4] += __uint_as_float(v.z << 16);
        a[5] += __uint_as_float(v.z & 0xffff0000u);
        a[6] += __uint_as_float(v.w << 16);
        a[7] += __uint_as_float(v.w & 0xffff0000u);
    };

    for (int base = beg; base < end; base += 64) {
        int cnt = min(64, end - base);
        int sv = (lane < cnt) ? __builtin_nontemporal_load(&csr[base + lane]) : 0;
        int k = 0;
        for (; k + 16 <= cnt; k += 16) {
            int s0 = __shfl(sv, k + grp);
            int s1 = __shfl(sv, k + 4 + grp);
            int s2 = __shfl(sv, k + 8 + grp);
            int s3 = __shfl(sv, k + 12 + grp);
            uint4 v0 = m4[(size_t)s0 * 16 + lj];
            uint4 v1 = m4[(size_t)s1 * 16 + lj];
            uint4 v2 = m4[(size_t)s2 * 16 + lj];
            uint4 v3 = m4[(size_t)s3 * 16 + lj];
            acc8(v0); acc8(v1); acc8(v2); acc8(v3);
        }
        for (; k + 4 <= cnt; k += 4) {      // wave-uniform
            int s = __shfl(sv, k + grp);
            uint4 v = m4[(size_t)s * 16 + lj];
            acc8(v);
        }
        int rem = cnt - k;                  // 0..3
        if (rem) {                          // wave-uniform
            int idx = k + grp;
            if (idx >= cnt) idx = cnt - 1;  // clamp; shuffle by ALL lanes
            int s = __shfl(sv, idx);
            if (grp < rem) {                // only accumulate predicated
                uint4 v = m4[(size_t)s * 16 + lj];
                acc8(v);
            }
        }
    }
#pragma unroll
    for (int q = 0; q < 8; ++q) a[q] += __shfl_xor(a[q], 16);
#pragma unroll
    for (int q = 0; q < 8; ++q) a[q] += __shfl_xor(a[q], 32);

    if (grp == 0) {
        float sc = dinv[node];
        float4 b0 = ((const float4*)bias)[lj * 2];
        float4 b1 = ((const float4*)bias)[lj * 2 + 1];
        float r0 = fmaxf(a[0] * sc + b0.x, 0.f);
        float r1 = fmaxf(a[1] * sc + b0.y, 0.f);
        float r2 = fmaxf(a[2] * sc + b0.z, 0.f);
        float r3 = fmaxf(a[3] * sc + b0.w, 0.f);
        float r4 = fmaxf(a[4] * sc + b1.x, 0.f);
        float r5 = fmaxf(a[5] * sc + b1.y, 0.f);
        float r6 = fmaxf(a[6] * sc + b1.z, 0.f);
        float r7 = fmaxf(a[7] * sc + b1.w, 0.f);
        uint4 o;
        o.x = pack_bf2(r0, r1);
        o.y = pack_bf2(r2, r3);
        o.z = pack_bf2(r4, r5);
        o.w = pack_bf2(r6, r7);
        *(uint4*)&outb[(size_t)node * 128 + lj * 8] = o;
    }
}

// Final: logits[r][:] += Hl(bf16)[r][:] @ Wl; then in-place log_softmax.
__global__ __launch_bounds__(256) void k_jk_lsm(const unsigned short* __restrict__ Hl,
                                                const float* __restrict__ Wl,
                                                float* __restrict__ logits) {
    __shared__ float At[32][68];
    __shared__ float Wt[32][64];
    int tid = threadIdx.x;
    int tx = tid & 15, ty = tid >> 4;
    int row0 = blockIdx.x * 64;
    float acc[4][4];
#pragma unroll
    for (int j = 0; j < 4; ++j)
#pragma unroll
        for (int c = 0; c < 4; ++c) acc[j][c] = 0.f;

    for (int kb = 0; kb < 128; kb += 32) {
#pragma unroll
        for (int i = 0; i < 2; ++i) {                 // Wl chunk 32x64
            int kr = ty + i * 16;
            float4 wv = *(const float4*)&Wl[(size_t)(kb + kr) * 64 + tx * 4];
            *(float4*)&Wt[kr][tx * 4] = wv;
        }
        {   // A chunk 64x32 from bf16, transposed store
            int r = tid >> 2, c8 = tid & 3;
            int gr = row0 + r;
            uint4 v = make_uint4(0, 0, 0, 0);
            if (gr < NN) v = *(const uint4*)&Hl[(size_t)gr * 128 + kb + c8 * 8];
            At[c8 * 8 + 0][r] = __uint_as_float(v.x << 16);
            At[c8 * 8 + 1][r] = __uint_as_float(v.x & 0xffff0000u);
            At[c8 * 8 + 2][r] = __uint_as_float(v.y << 16);
            At[c8 * 8 + 3][r] = __uint_as_float(v.y & 0xffff0000u);
            At[c8 * 8 + 4][r] = __uint_as_float(v.z << 16);
            At[c8 * 8 + 5][r] = __uint_as_float(v.z & 0xffff0000u);
            At[c8 * 8 + 6][r] = __uint_as_float(v.w << 16);
            At[c8 * 8 + 7][r] = __uint_as_float(v.w & 0xffff0000u);
        }
        __syncthreads();
#pragma unroll 4
        for (int k = 0; k < 32; ++k) {
            float4 a4 = *(const float4*)&At[k][ty * 4];
            float4 wv = *(const float4*)&Wt[k][tx * 4];
            float a[4] = {a4.x, a4.y, a4.z, a4.w};
#pragma unroll
            for (int j = 0; j < 4; ++j) {
                acc[j][0] += a[j] * wv.x;
                acc[j][1] += a[j] * wv.y;
                acc[j][2] += a[j] * wv.z;
                acc[j][3] += a[j] * wv.w;
            }
        }
        __syncthreads();
    }
#pragma unroll
    for (int j = 0; j < 4; ++j) {
        int r = row0 + ty * 4 + j;
        if (r < NN) {
            float4 prev = *(const float4*)&logits[(size_t)r * 64 + tx * 4];
            float v0 = prev.x + acc[j][0];
            float v1 = prev.y + acc[j][1];
            float v2 = prev.z + acc[j][2];
            float v3 = prev.w + acc[j][3];
            float mx = fmaxf(fmaxf(v0, v1), fmaxf(v2, v3));
#pragma unroll
            for (int s = 1; s < 16; s <<= 1) mx = fmaxf(mx, __shfl_xor(mx, s, 16));
            float e0 = expf(v0 - mx), e1 = expf(v1 - mx);
            float e2 = expf(v2 - mx), e3 = expf(v3 - mx);
            float sum = (e0 + e1) + (e2 + e3);
#pragma unroll
            for (int s = 1; s < 16; s <<= 1) sum += __shfl_xor(sum, s, 16);
            float ls = logf(sum) + mx;
            float4 o = make_float4(v0 - ls, v1 - ls, v2 - ls, v3 - ls);
            *(float4*)&logits[(size_t)r * 64 + tx * 4] = o;
        }
    }
}

// ---------------- launch ----------------

extern "C" void kernel_launch(void* const* d_in, const int* in_sizes, int n_in,
                              void* d_out, int out_size, void* d_ws, size_t ws_size,
                              hipStream_t stream) {
    const float* x    = (const float*)d_in[0];
    const int*   ei   = (const int*)d_in[1];
    const float* W[4] = {(const float*)d_in[2], (const float*)d_in[4],
                         (const float*)d_in[6], (const float*)d_in[8]};
    const float* b[4] = {(const float*)d_in[3], (const float*)d_in[5],
                         (const float*)d_in[7], (const float*)d_in[9]};
    const float* linW = (const float*)d_in[10];
    const float* linb = (const float*)d_in[11];
    float* out = (float*)d_out;

    char* wp = (char*)d_ws;
    auto alloc = [&](size_t bytes) {
        void* p = (void*)wp;
        wp += (bytes + 255) & ~(size_t)255;
        return p;
    };
    int*   flag   = (int*)  alloc(4);
    int*   deg    = (int*)  alloc((size_t)NN * 4);
    float* dinv   = (float*)alloc((size_t)NN * 4);
    int*   rowptr = (int*)  alloc((size_t)(NN + 1) * 4);
    int*   cursor = (int*)  alloc((size_t)NN * 4);
    int*   bsum   = (int*)  alloc(512);
    int*   boff   = (int*)  alloc(512);
    int*   csr    = (int*)  alloc((size_t)NTOT * 4);
    unsigned short* WT  = (unsigned short*)alloc((size_t)4 * 128 * 128 * 2);
    unsigned short* WjT = (unsigned short*)alloc((size_t)4 * 64 * 128 * 2);
    unsigned short* xb   = (unsigned short*)alloc((size_t)NN * 128 * 2);  // bf16 x
    unsigned short* bufM = (unsigned short*)alloc((size_t)NN * 128 * 2);  // messages
    unsigned short* bufB = (unsigned short*)alloc((size_t)NN * 128 * 2);  // bf16 h
    unsigned short* bufC = (unsigned short*)alloc((size_t)NN * 128 * 2);

    dim3 blk(256);
    k_init   <<<391, blk, 0, stream>>>(flag, deg);
    k_prep   <<<384, blk, 0, stream>>>(W[0], W[1], W[2], W[3], linW, WT, WjT);
    k_detect <<<1024, blk, 0, stream>>>(ei, flag);
    k_xcvt   <<<6250, blk, 0, stream>>>(x, (unsigned int*)xb);
    k_hist8  <<<6656, blk, 0, stream>>>(ei, flag, deg);
    k_scanA  <<<98, blk, 0, stream>>>(deg, rowptr, bsum, dinv);
    k_scanB  <<<1, dim3(128), 0, stream>>>(bsum, boff, rowptr);
    k_scanC  <<<391, blk, 0, stream>>>(rowptr, boff, cursor);
    k_scat3  <<<6656, blk, 0, stream>>>(ei, flag, cursor, rowptr, csr);

    const unsigned short* lin[4] = {xb, bufB, bufC, bufB};
    unsigned short*      lout[4] = {bufB, bufC, bufB, bufC};
    for (int l = 0; l < 4; ++l) {
        const unsigned short* wjt = (l == 0) ? nullptr : WjT + (size_t)(l - 1) * 64 * 128;
        k_mmf<<<1563, blk, 0, stream>>>(lin[l], WT + (size_t)l * 128 * 128, dinv,
                                        wjt, linb, out, l == 1 ? 1 : 0, bufM);
        k_agg<<<25000, blk, 0, stream>>>(rowptr, csr, (const uint4*)bufM, dinv,
                                         b[l], lout[l]);
    }
    k_jk_lsm<<<1563, blk, 0, stream>>>(lout[3], linW + (size_t)3 * 128 * 64, out);
}

// Round 13
// 570.111 us; speedup vs baseline: 1.5191x; 1.0445x over previous
//
#include <hip/hip_runtime.h>
#include <cstdint>
#include <cstddef>

#define NN 100000
#define NE 1600000
#define NTOT (NE + NN)      // 1700000 edges incl self-loops
#define HF 128
#define OF 64
#define SHARD 12500         // NN/8 dst-range per XCD
#define EPB 1924            // edges per chunk: 832*1924 >= NE
#define NPB 16              // shard nodes per chunk: 832*16 >= SHARD

typedef short bfrag_t __attribute__((ext_vector_type(8)));   // 8 bf16 = 4 VGPR
typedef float f4v     __attribute__((ext_vector_type(4)));   // MFMA acc

// ---------------- helpers ----------------

__device__ __forceinline__ unsigned int f2bf_rne(float f) {
    unsigned int u = __float_as_uint(f);
    return (u + 0x7fffu + ((u >> 16) & 1u)) >> 16;
}
__device__ __forceinline__ unsigned int pack_bf2(float lo, float hi) {
    return f2bf_rne(lo) | (f2bf_rne(hi) << 16);
}

// ---------------- graph preprocessing ----------------

__global__ __launch_bounds__(256) void k_init(int* flag, int* deg) {
    int i = blockIdx.x * 256 + threadIdx.x;
    if (i == 0) *flag = 0;
    if (i < NN) deg[i] = 1;   // self-loop
}

__global__ __launch_bounds__(256) void k_detect(const int* ei, int* flag) {
    int t = blockIdx.x * blockDim.x + threadIdx.x;
    int v = 0;
    for (int i = t; i < NE; i += gridDim.x * blockDim.x) v |= ei[2 * i + 1];
    unsigned long long b = __ballot(v != 0);
    if ((threadIdx.x & 63) == 0 && b) atomicOr(flag, 1);
}

__device__ __forceinline__ int edge_src(const int* ei, int e, bool is64) {
    return is64 ? ei[2 * e] : ei[e];
}
__device__ __forceinline__ int edge_dst(const int* ei, int e, bool is64) {
    return is64 ? ei[2 * (NE + e)] : ei[NE + e];
}

// XCD-sharded histogram: deg lines each touched by ONE XCD -> local atomics.
__global__ __launch_bounds__(256) void k_hist8(const int* __restrict__ ei,
                                               const int* __restrict__ flag,
                                               int* __restrict__ deg) {
    int x = blockIdx.x & 7, c = blockIdx.x >> 3;
    bool is64 = (*flag) == 0;
    int d0 = x * SHARD;
    int ebeg = c * EPB;
    int eend = min(NE, ebeg + EPB);
    for (int e = ebeg + (int)threadIdx.x; e < eend; e += 256) {
        int d = edge_dst(ei, e, is64);
        if ((unsigned)(d - d0) < SHARD) atomicAdd(&deg[d], 1);
    }
}

// exclusive scan of deg[N] -> rowptr (partial), also dinv = rsqrt(deg)
__global__ __launch_bounds__(256) void k_scanA(const int* deg, int* rowptr, int* bsum,
                                               float* dinv) {
    __shared__ int sh[256];
    int tid = threadIdx.x;
    int base = blockIdx.x * 1024 + tid * 4;
    int v0 = 0, v1 = 0, v2 = 0, v3 = 0;
    if (base + 0 < NN) v0 = deg[base + 0];
    if (base + 1 < NN) v1 = deg[base + 1];
    if (base + 2 < NN) v2 = deg[base + 2];
    if (base + 3 < NN) v3 = deg[base + 3];
    if (base + 0 < NN) dinv[base + 0] = rsqrtf((float)v0);
    if (base + 1 < NN) dinv[base + 1] = rsqrtf((float)v1);
    if (base + 2 < NN) dinv[base + 2] = rsqrtf((float)v2);
    if (base + 3 < NN) dinv[base + 3] = rsqrtf((float)v3);
    int s = v0 + v1 + v2 + v3;
    sh[tid] = s;
    __syncthreads();
    for (int off = 1; off < 256; off <<= 1) {
        int t = (tid >= off) ? sh[tid - off] : 0;
        __syncthreads();
        sh[tid] += t;
        __syncthreads();
    }
    int run = sh[tid] - s;
    if (base + 0 < NN) rowptr[base + 0] = run; run += v0;
    if (base + 1 < NN) rowptr[base + 1] = run; run += v1;
    if (base + 2 < NN) rowptr[base + 2] = run; run += v2;
    if (base + 3 < NN) rowptr[base + 3] = run;
    if (tid == 255) bsum[blockIdx.x] = sh[255];
}

__global__ __launch_bounds__(128) void k_scanB(const int* bsum, int* boff, int* rowptr) {
    __shared__ int sh[128];
    int tid = threadIdx.x;
    int v = (tid < 98) ? bsum[tid] : 0;
    sh[tid] = v;
    __syncthreads();
    for (int off = 1; off < 128; off <<= 1) {
        int t = (tid >= off) ? sh[tid - off] : 0;
        __syncthreads();
        sh[tid] += t;
        __syncthreads();
    }
    if (tid < 98) boff[tid] = sh[tid] - v;
    if (tid == 0) rowptr[NN] = NTOT;
}

__global__ __launch_bounds__(256) void k_scanC(int* rowptr, const int* boff, int* cursor) {
    int i = blockIdx.x * 256 + threadIdx.x;
    if (i < NN) {
        int r = rowptr[i] + boff[i >> 10];
        rowptr[i] = r;
        cursor[i] = r + 1;   // slot r reserved for the self-loop
    }
}

// XCD-sharded CSR fill with shard-local atomic cursor.
__global__ __launch_bounds__(256) void k_scat3(const int* __restrict__ ei,
                                               const int* __restrict__ flag,
                                               int* __restrict__ cursor,
                                               const int* __restrict__ rowptr,
                                               int* __restrict__ csr) {
    int x = blockIdx.x & 7, c = blockIdx.x >> 3;
    bool is64 = (*flag) == 0;
    int d0 = x * SHARD;
    int nbeg = d0 + c * NPB;
    int nend = min(d0 + SHARD, nbeg + NPB);
    for (int nd = nbeg + (int)threadIdx.x; nd < nend; nd += 256)
        csr[rowptr[nd]] = nd;                       // self-loop slot
    int ebeg = c * EPB;
    int eend = min(NE, ebeg + EPB);
    for (int e = ebeg + (int)threadIdx.x; e < eend; e += 256) {
        int d = edge_dst(ei, e, is64);
        if ((unsigned)(d - d0) < SHARD) {
            int s = edge_src(ei, e, is64);
            int pos = atomicAdd(&cursor[d], 1);
            csr[pos] = s;
        }
    }
}

// ---------------- x f32 -> bf16 ----------------
__global__ __launch_bounds__(256) void k_xcvt(const float* __restrict__ x,
                                              unsigned int* __restrict__ xb4) {
    int i = blockIdx.x * 256 + threadIdx.x;      // one uint4 (8 bf16) per thread
    if (i >= NN * 16) return;
    float4 v0 = ((const float4*)x)[(size_t)i * 2];
    float4 v1 = ((const float4*)x)[(size_t)i * 2 + 1];
    uint4 o;
    o.x = pack_bf2(v0.x, v0.y);
    o.y = pack_bf2(v0.z, v0.w);
    o.z = pack_bf2(v1.x, v1.y);
    o.w = pack_bf2(v1.z, v1.w);
    ((uint4*)xb4)[i] = o;
}

// ---------------- weight prep: bf16 + transpose to [n][k] ----------------
__global__ __launch_bounds__(256) void k_prep(const float* __restrict__ W0,
                                              const float* __restrict__ W1,
                                              const float* __restrict__ W2,
                                              const float* __restrict__ W3,
                                              const float* __restrict__ linW,
                                              unsigned short* __restrict__ WT,
                                              unsigned short* __restrict__ WjT) {
    int idx = blockIdx.x * 256 + threadIdx.x;
    if (idx < 4 * 128 * 128) {
        int l = idx >> 14, r = idx & 16383, n = r >> 7, k = r & 127;
        const float* Wl = (l == 0) ? W0 : (l == 1) ? W1 : (l == 2) ? W2 : W3;
        WT[idx] = (unsigned short)f2bf_rne(Wl[k * 128 + n]);
    } else if (idx < 4 * 128 * 128 + 4 * 64 * 128) {
        int i2 = idx - 65536;
        int l = i2 >> 13, r = i2 & 8191, n = r >> 7, k = r & 127;
        WjT[i2] = (unsigned short)f2bf_rne(linW[(size_t)(l * 128 + k) * 64 + n]);
    }
}

// ---------------- MFMA matmul: m = bf16(dinv * (A @ W)) ----------------
// A bf16 [N][128]; A fragments direct from global (contiguous 16 B per lane).
__global__ __launch_bounds__(256) void k_mmf(const unsigned short* __restrict__ A,
                                             const unsigned short* __restrict__ WT,
                                             const float* __restrict__ dinv,
                                             unsigned short* __restrict__ m16) {
    __shared__ unsigned short Wlds[128 * 128];   // 32 KB
    int tid = threadIdx.x;
    int row0 = blockIdx.x * 64;

    for (int c = tid; c < 2048; c += 256) {       // W^T, swizzled
        int row = c >> 4, c16 = c & 15;
        uint4 v = *(const uint4*)&WT[row * 128 + c16 * 8];
        *(uint4*)((char*)Wlds + row * 256 + ((c16 * 16) ^ ((row & 7) << 4))) = v;
    }

    int lane = tid & 63, w = tid >> 6;
    int r15 = lane & 15, q = lane >> 4;
    int xo = (r15 & 7) << 4;

    int arow = row0 + 16 * w + r15;
    bool av = arow < NN;
    bfrag_t afr[4];
#pragma unroll
    for (int ks = 0; ks < 4; ++ks) {
        bfrag_t z = {0, 0, 0, 0, 0, 0, 0, 0};
        afr[ks] = av ? *(const bfrag_t*)&A[(size_t)arow * 128 + ks * 32 + q * 8] : z;
    }
    __syncthreads();

    f4v acc[8];
#pragma unroll
    for (int i = 0; i < 8; ++i) acc[i] = (f4v){0.f, 0.f, 0.f, 0.f};

#pragma unroll
    for (int ks = 0; ks < 4; ++ks) {
        int ko = ks * 64 + q * 16;
#pragma unroll
        for (int nb = 0; nb < 8; ++nb) {
            bfrag_t b = *(const bfrag_t*)((const char*)Wlds + (nb * 16 + r15) * 256 + (ko ^ xo));
            acc[nb] = __builtin_amdgcn_mfma_f32_16x16x32_bf16(afr[ks], b, acc[nb], 0, 0, 0);
        }
    }

#pragma unroll
    for (int reg = 0; reg < 4; ++reg) {
        int gr = row0 + 16 * w + q * 4 + reg;
        if (gr < NN) {
            float sc = dinv[gr];
#pragma unroll
            for (int nb = 0; nb < 8; ++nb)
                m16[(size_t)gr * 128 + nb * 16 + r15] =
                    (unsigned short)f2bf_rne(acc[nb][reg] * sc);
        }
    }
}

// h_out[d][:] = bf16(relu(dinv[d] * sum_{s in N(d)} bf16m[s][:] + b))
// one wave per node; 4 groups of 16 lanes gather full 256 B rows (16 B/lane);
// 16-edge inner step = 4 independent gathers in flight. All __shfl executed
// by ALL lanes (wave-uniform); grp0 writes the full 256 B bf16 output row.
__global__ __launch_bounds__(256) void k_agg(const int* __restrict__ rowptr,
                                             const int* __restrict__ csr,
                                             const uint4* __restrict__ m4,
                                             const float* __restrict__ dinv,
                                             const float* __restrict__ bias,
                                             unsigned short* __restrict__ outb) {
    int w = threadIdx.x >> 6, lane = threadIdx.x & 63;
    int grp = lane >> 4, lj = lane & 15;
    int node = blockIdx.x * 4 + w;
    if (node >= NN) return;
    int beg = rowptr[node], end = rowptr[node + 1];

    float a[8];
#pragma unroll
    for (int q = 0; q < 8; ++q) a[q] = 0.f;

    auto acc8 = [&](uint4 v) {
        a[0] += __uint_as_float(v.x << 16);
        a[1] += __uint_as_float(v.x & 0xffff0000u);
        a[2] += __uint_as_float(v.y << 16);
        a[3] += __uint_as_float(v.y & 0xffff0000u);
        a[4] += __uint_as_float(v.z << 16);
        a[5] += __uint_as_float(v.z & 0xffff0000u);
        a[6] += __uint_as_float(v.w << 16);
        a[7] += __uint_as_float(v.w & 0xffff0000u);
    };

    for (int base = beg; base < end; base += 64) {
        int cnt = min(64, end - base);
        int sv = (lane < cnt) ? csr[base + lane] : 0;
        int k = 0;
        for (; k + 16 <= cnt; k += 16) {
            int s0 = __shfl(sv, k + grp);
            int s1 = __shfl(sv, k + 4 + grp);
            int s2 = __shfl(sv, k + 8 + grp);
            int s3 = __shfl(sv, k + 12 + grp);
            uint4 v0 = m4[(size_t)s0 * 16 + lj];
            uint4 v1 = m4[(size_t)s1 * 16 + lj];
            uint4 v2 = m4[(size_t)s2 * 16 + lj];
            uint4 v3 = m4[(size_t)s3 * 16 + lj];
            acc8(v0); acc8(v1); acc8(v2); acc8(v3);
        }
        for (; k + 4 <= cnt; k += 4) {      // wave-uniform
            int s = __shfl(sv, k + grp);
            uint4 v = m4[(size_t)s * 16 + lj];
            acc8(v);
        }
        int rem = cnt - k;                  // 0..3
        if (rem) {                          // wave-uniform
            int idx = k + grp;
            if (idx >= cnt) idx = cnt - 1;  // clamp; shuffle by ALL lanes
            int s = __shfl(sv, idx);
            if (grp < rem) {                // only accumulate predicated
                uint4 v = m4[(size_t)s * 16 + lj];
                acc8(v);
            }
        }
    }
#pragma unroll
    for (int q = 0; q < 8; ++q) a[q] += __shfl_xor(a[q], 16);
#pragma unroll
    for (int q = 0; q < 8; ++q) a[q] += __shfl_xor(a[q], 32);

    if (grp == 0) {
        float sc = dinv[node];
        float4 b0 = ((const float4*)bias)[lj * 2];
        float4 b1 = ((const float4*)bias)[lj * 2 + 1];
        float r0 = fmaxf(a[0] * sc + b0.x, 0.f);
        float r1 = fmaxf(a[1] * sc + b0.y, 0.f);
        float r2 = fmaxf(a[2] * sc + b0.z, 0.f);
        float r3 = fmaxf(a[3] * sc + b0.w, 0.f);
        float r4 = fmaxf(a[4] * sc + b1.x, 0.f);
        float r5 = fmaxf(a[5] * sc + b1.y, 0.f);
        float r6 = fmaxf(a[6] * sc + b1.z, 0.f);
        float r7 = fmaxf(a[7] * sc + b1.w, 0.f);
        uint4 o;
        o.x = pack_bf2(r0, r1);
        o.y = pack_bf2(r2, r3);
        o.z = pack_bf2(r4, r5);
        o.w = pack_bf2(r6, r7);
        *(uint4*)&outb[(size_t)node * 128 + lj * 8] = o;
    }
}

// ---------------- final: logits = sum_l h_l @ Wjk_l + linb; log_softmax ----------------
// All 4 Wjk^T staged in 64 KB LDS; h_l fragments direct from global; in-register
// log-softmax over each 64-col row (4 cols/lane x 16-lane shfl groups).
__global__ __launch_bounds__(256) void k_jk4(const unsigned short* __restrict__ h0,
                                             const unsigned short* __restrict__ h1,
                                             const unsigned short* __restrict__ h2,
                                             const unsigned short* __restrict__ h3,
                                             const unsigned short* __restrict__ WjT,
                                             const float* __restrict__ linb,
                                             float* __restrict__ out) {
    __shared__ unsigned short Wjlds[4 * 64 * 128];   // 64 KB, swizzled
    int tid = threadIdx.x;
    int row0 = blockIdx.x * 64;

    for (int c = tid; c < 4096; c += 256) {      // 256 rows (l*64+n) x 128
        int row = c >> 4, c16 = c & 15;
        uint4 v = *(const uint4*)&WjT[row * 128 + c16 * 8];
        *(uint4*)((char*)Wjlds + row * 256 + ((c16 * 16) ^ ((row & 7) << 4))) = v;
    }

    int lane = tid & 63, w = tid >> 6;
    int r15 = lane & 15, q = lane >> 4;
    int xo = (r15 & 7) << 4;
    int arow = row0 + 16 * w + r15;
    bool av = arow < NN;
    const unsigned short* hs[4] = {h0, h1, h2, h3};

    __syncthreads();

    f4v accj[4];
#pragma unroll
    for (int i = 0; i < 4; ++i) accj[i] = (f4v){0.f, 0.f, 0.f, 0.f};

#pragma unroll
    for (int l = 0; l < 4; ++l) {
        bfrag_t afr[4];
#pragma unroll
        for (int ks = 0; ks < 4; ++ks) {
            bfrag_t z = {0, 0, 0, 0, 0, 0, 0, 0};
            afr[ks] = av ? *(const bfrag_t*)&hs[l][(size_t)arow * 128 + ks * 32 + q * 8] : z;
        }
#pragma unroll
        for (int ks = 0; ks < 4; ++ks) {
            int ko = ks * 64 + q * 16;
#pragma unroll
            for (int jb = 0; jb < 4; ++jb) {
                bfrag_t b = *(const bfrag_t*)((const char*)Wjlds
                            + (l * 64 + jb * 16 + r15) * 256 + (ko ^ xo));
                accj[jb] = __builtin_amdgcn_mfma_f32_16x16x32_bf16(afr[ks], b, accj[jb], 0, 0, 0);
            }
        }
    }

    // epilogue + in-register log_softmax; lanes q*16..q*16+15 share row gr.
#pragma unroll
    for (int reg = 0; reg < 4; ++reg) {
        int gr = row0 + 16 * w + q * 4 + reg;    // uniform across the 16-lane group
        float v0 = accj[0][reg] + linb[r15];
        float v1 = accj[1][reg] + linb[16 + r15];
        float v2 = accj[2][reg] + linb[32 + r15];
        float v3 = accj[3][reg] + linb[48 + r15];
        float mx = fmaxf(fmaxf(v0, v1), fmaxf(v2, v3));
#pragma unroll
        for (int s = 1; s < 16; s <<= 1) mx = fmaxf(mx, __shfl_xor(mx, s, 16));
        float sum = expf(v0 - mx) + expf(v1 - mx) + expf(v2 - mx) + expf(v3 - mx);
#pragma unroll
        for (int s = 1; s < 16; s <<= 1) sum += __shfl_xor(sum, s, 16);
        float ls = logf(sum) + mx;
        if (gr < NN) {
            out[(size_t)gr * 64 + r15]      = v0 - ls;
            out[(size_t)gr * 64 + 16 + r15] = v1 - ls;
            out[(size_t)gr * 64 + 32 + r15] = v2 - ls;
            out[(size_t)gr * 64 + 48 + r15] = v3 - ls;
        }
    }
}

// ---------------- launch ----------------

extern "C" void kernel_launch(void* const* d_in, const int* in_sizes, int n_in,
                              void* d_out, int out_size, void* d_ws, size_t ws_size,
                              hipStream_t stream) {
    const float* x    = (const float*)d_in[0];
    const int*   ei   = (const int*)d_in[1];
    const float* W[4] = {(const float*)d_in[2], (const float*)d_in[4],
                         (const float*)d_in[6], (const float*)d_in[8]};
    const float* b[4] = {(const float*)d_in[3], (const float*)d_in[5],
                         (const float*)d_in[7], (const float*)d_in[9]};
    const float* linW = (const float*)d_in[10];
    const float* linb = (const float*)d_in[11];
    float* out = (float*)d_out;

    char* wp = (char*)d_ws;
    auto alloc = [&](size_t bytes) {
        void* p = (void*)wp;
        wp += (bytes + 255) & ~(size_t)255;
        return p;
    };
    int*   flag   = (int*)  alloc(4);
    int*   deg    = (int*)  alloc((size_t)NN * 4);
    float* dinv   = (float*)alloc((size_t)NN * 4);
    int*   rowptr = (int*)  alloc((size_t)(NN + 1) * 4);
    int*   cursor = (int*)  alloc((size_t)NN * 4);
    int*   bsum   = (int*)  alloc(512);
    int*   boff   = (int*)  alloc(512);
    int*   csr    = (int*)  alloc((size_t)NTOT * 4);
    unsigned short* WT  = (unsigned short*)alloc((size_t)4 * 128 * 128 * 2);
    unsigned short* WjT = (unsigned short*)alloc((size_t)4 * 64 * 128 * 2);
    unsigned short* xb   = (unsigned short*)alloc((size_t)NN * 128 * 2);  // bf16 x
    unsigned short* bufM = (unsigned short*)alloc((size_t)NN * 128 * 2);  // messages
    unsigned short* h[4];
    for (int l = 0; l < 4; ++l)
        h[l] = (unsigned short*)alloc((size_t)NN * 128 * 2);              // bf16 h_l

    dim3 blk(256);
    k_init   <<<391, blk, 0, stream>>>(flag, deg);
    k_prep   <<<384, blk, 0, stream>>>(W[0], W[1], W[2], W[3], linW, WT, WjT);
    k_detect <<<1024, blk, 0, stream>>>(ei, flag);
    k_xcvt   <<<6250, blk, 0, stream>>>(x, (unsigned int*)xb);
    k_hist8  <<<6656, blk, 0, stream>>>(ei, flag, deg);
    k_scanA  <<<98, blk, 0, stream>>>(deg, rowptr, bsum, dinv);
    k_scanB  <<<1, dim3(128), 0, stream>>>(bsum, boff, rowptr);
    k_scanC  <<<391, blk, 0, stream>>>(rowptr, boff, cursor);
    k_scat3  <<<6656, blk, 0, stream>>>(ei, flag, cursor, rowptr, csr);

    const unsigned short* lin[4] = {xb, h[0], h[1], h[2]};
    for (int l = 0; l < 4; ++l) {
        k_mmf<<<1563, blk, 0, stream>>>(lin[l], WT + (size_t)l * 128 * 128, dinv,
                                        bufM);
        k_agg<<<25000, blk, 0, stream>>>(rowptr, csr, (const uint4*)bufM, dinv,
                                         b[l], h[l]);
    }
    k_jk4<<<1563, blk, 0, stream>>>(h[0], h[1], h[2], h[3], WjT, linb, out);
}

// Round 14
// 527.406 us; speedup vs baseline: 1.6421x; 1.0810x over previous
//
#include <hip/hip_runtime.h>
#include <cstdint>
#include <cstddef>

#define NN 100000
#define NE 1600000
#define NTOT (NE + NN)      // 1700000 edges incl self-loops
#define HF 128
#define OF 64
#define SHARD 12500         // NN/8 dst-range per XCD
#define BCHUNK 2048         // edges per k_bin block
#define BCAP 210000         // per-shard bin capacity (mean 200K, +25 sigma)

typedef short bfrag_t __attribute__((ext_vector_type(8)));   // 8 bf16 = 4 VGPR
typedef float f4v     __attribute__((ext_vector_type(4)));   // MFMA acc

// ---------------- helpers ----------------

__device__ __forceinline__ unsigned int f2bf_rne(float f) {
    unsigned int u = __float_as_uint(f);
    return (u + 0x7fffu + ((u >> 16) & 1u)) >> 16;
}
__device__ __forceinline__ unsigned int pack_bf2(float lo, float hi) {
    return f2bf_rne(lo) | (f2bf_rne(hi) << 16);
}

// ---------------- graph preprocessing ----------------

__global__ __launch_bounds__(256) void k_init(int* flag, int* deg, int* gcnt) {
    int i = blockIdx.x * 256 + threadIdx.x;
    if (i == 0) *flag = 0;
    if (i < 8) gcnt[i] = 0;
    if (i < NN) deg[i] = 1;   // self-loop
}

__global__ __launch_bounds__(256) void k_detect(const int* ei, int* flag) {
    int t = blockIdx.x * blockDim.x + threadIdx.x;
    int v = 0;
    for (int i = t; i < NE; i += gridDim.x * blockDim.x) v |= ei[2 * i + 1];
    unsigned long long b = __ballot(v != 0);
    if ((threadIdx.x & 63) == 0 && b) atomicOr(flag, 1);
}

__device__ __forceinline__ int edge_src_nt(const int* ei, int e, bool is64) {
    return is64 ? __builtin_nontemporal_load(&ei[2 * e])
                : __builtin_nontemporal_load(&ei[e]);
}
__device__ __forceinline__ int edge_dst_nt(const int* ei, int e, bool is64) {
    return is64 ? __builtin_nontemporal_load(&ei[2 * (NE + e)])
                : __builtin_nontemporal_load(&ei[NE + e]);
}

// Single-pass shard binning: read each edge ONCE, LDS-bin by dst shard,
// write coalesced (d,s) records into 8 per-shard global segments.
__global__ __launch_bounds__(256) void k_bin(const int* __restrict__ ei,
                                             const int* __restrict__ flag,
                                             int* __restrict__ gcnt,
                                             uint2* __restrict__ binbuf) {
    __shared__ uint2 bins[8][640];     // 40 KB; 640 cap = +32 sigma vs mean 256
    __shared__ int cnt[8], base[8];
    int tid = threadIdx.x;
    if (tid < 8) cnt[tid] = 0;
    __syncthreads();
    bool is64 = (*flag) == 0;
    int ebeg = blockIdx.x * BCHUNK;
    int eend = min(NE, ebeg + BCHUNK);
    for (int e = ebeg + tid; e < eend; e += 256) {
        int d = edge_dst_nt(ei, e, is64);
        int s = edge_src_nt(ei, e, is64);
        int x = (unsigned)d / SHARD;
        int p = atomicAdd(&cnt[x], 1);
        if (p < 640) bins[x][p] = make_uint2((unsigned)d, (unsigned)s);
    }
    __syncthreads();
    if (tid < 8) {
        int c = min(cnt[tid], 640);
        cnt[tid] = c;
        base[tid] = atomicAdd(&gcnt[tid], c);
    }
    __syncthreads();
    for (int x = 0; x < 8; ++x) {
        int c = cnt[x], b0 = base[x];
        for (int i = tid; i < c; i += 256)
            binbuf[(size_t)x * BCAP + b0 + i] = bins[x][i];
    }
}

// Sharded histogram + rank from bins: shard x on blocks b%8 (XCD round-robin),
// deg atomics local to one XCD; rank stored in shard-private array (no
// cross-XCD false sharing).
__global__ __launch_bounds__(256) void k_hist8b(const int* __restrict__ gcnt,
                                                const uint2* __restrict__ binbuf,
                                                int* __restrict__ deg,
                                                int* __restrict__ rankbuf) {
    int x = blockIdx.x & 7, blk = blockIdx.x >> 3;
    int n = gcnt[x];
    int stride = (gridDim.x >> 3) * 256;
    for (int i = blk * 256 + (int)threadIdx.x; i < n; i += stride) {
        uint2 r = binbuf[(size_t)x * BCAP + i];
        rankbuf[(size_t)x * BCAP + i] = atomicAdd(&deg[r.x], 1);
    }
}

// exclusive scan of deg[N] -> rowptr (partial), also dinv = rsqrt(deg)
__global__ __launch_bounds__(256) void k_scanA(const int* deg, int* rowptr, int* bsum,
                                               float* dinv) {
    __shared__ int sh[256];
    int tid = threadIdx.x;
    int base = blockIdx.x * 1024 + tid * 4;
    int v0 = 0, v1 = 0, v2 = 0, v3 = 0;
    if (base + 0 < NN) v0 = deg[base + 0];
    if (base + 1 < NN) v1 = deg[base + 1];
    if (base + 2 < NN) v2 = deg[base + 2];
    if (base + 3 < NN) v3 = deg[base + 3];
    if (base + 0 < NN) dinv[base + 0] = rsqrtf((float)v0);
    if (base + 1 < NN) dinv[base + 1] = rsqrtf((float)v1);
    if (base + 2 < NN) dinv[base + 2] = rsqrtf((float)v2);
    if (base + 3 < NN) dinv[base + 3] = rsqrtf((float)v3);
    int s = v0 + v1 + v2 + v3;
    sh[tid] = s;
    __syncthreads();
    for (int off = 1; off < 256; off <<= 1) {
        int t = (tid >= off) ? sh[tid - off] : 0;
        __syncthreads();
        sh[tid] += t;
        __syncthreads();
    }
    int run = sh[tid] - s;
    if (base + 0 < NN) rowptr[base + 0] = run; run += v0;
    if (base + 1 < NN) rowptr[base + 1] = run; run += v1;
    if (base + 2 < NN) rowptr[base + 2] = run; run += v2;
    if (base + 3 < NN) rowptr[base + 3] = run;
    if (tid == 255) bsum[blockIdx.x] = sh[255];
}

__global__ __launch_bounds__(128) void k_scanB(const int* bsum, int* boff, int* rowptr) {
    __shared__ int sh[128];
    int tid = threadIdx.x;
    int v = (tid < 98) ? bsum[tid] : 0;
    sh[tid] = v;
    __syncthreads();
    for (int off = 1; off < 128; off <<= 1) {
        int t = (tid >= off) ? sh[tid - off] : 0;
        __syncthreads();
        sh[tid] += t;
        __syncthreads();
    }
    if (tid < 98) boff[tid] = sh[tid] - v;
    if (tid == 0) rowptr[NN] = NTOT;
}

// finalize rowptr AND place the self-loop in slot 0 of each row
__global__ __launch_bounds__(256) void k_scanC(int* rowptr, const int* boff, int* csr) {
    int i = blockIdx.x * 256 + threadIdx.x;
    if (i < NN) {
        int r = rowptr[i] + boff[i >> 10];
        rowptr[i] = r;
        csr[r] = i;          // self-loop (ranks from k_hist8b start at 1)
    }
}

// Rank-based CSR fill from bins: pure independent writes, no atomics.
__global__ __launch_bounds__(256) void k_scat4(const int* __restrict__ gcnt,
                                               const uint2* __restrict__ binbuf,
                                               const int* __restrict__ rankbuf,
                                               const int* __restrict__ rowptr,
                                               int* __restrict__ csr) {
    int x = blockIdx.x & 7, blk = blockIdx.x >> 3;
    int n = gcnt[x];
    int stride = (gridDim.x >> 3) * 256;
    for (int i = blk * 256 + (int)threadIdx.x; i < n; i += stride) {
        uint2 r = binbuf[(size_t)x * BCAP + i];
        int rk = rankbuf[(size_t)x * BCAP + i];
        csr[rowptr[r.x] + rk] = (int)r.y;
    }
}

// ---------------- weight prep: bf16 + transpose to [n][k] ----------------
__global__ __launch_bounds__(256) void k_prep(const float* __restrict__ W0,
                                              const float* __restrict__ W1,
                                              const float* __restrict__ W2,
                                              const float* __restrict__ W3,
                                              const float* __restrict__ linW,
                                              unsigned short* __restrict__ WT,
                                              unsigned short* __restrict__ WjT) {
    int idx = blockIdx.x * 256 + threadIdx.x;
    if (idx < 4 * 128 * 128) {
        int l = idx >> 14, r = idx & 16383, n = r >> 7, k = r & 127;
        const float* Wl = (l == 0) ? W0 : (l == 1) ? W1 : (l == 2) ? W2 : W3;
        WT[idx] = (unsigned short)f2bf_rne(Wl[k * 128 + n]);
    } else if (idx < 4 * 128 * 128 + 4 * 64 * 128) {
        int i2 = idx - 65536;
        int l = i2 >> 13, r = i2 & 8191, n = r >> 7, k = r & 127;
        WjT[i2] = (unsigned short)f2bf_rne(linW[(size_t)(l * 128 + k) * 64 + n]);
    }
}

// ---------------- MFMA matmul: m = bf16(dinv * (A @ W)) ----------------
// A fragments direct from global (contiguous 16 B per lane). If A32 != null
// (layer 0), read f32 and convert in-register (replaces the old k_xcvt pass).
__global__ __launch_bounds__(256) void k_mmf(const unsigned short* __restrict__ A,
                                             const float* __restrict__ A32,
                                             const unsigned short* __restrict__ WT,
                                             const float* __restrict__ dinv,
                                             unsigned short* __restrict__ m16) {
    __shared__ unsigned short Wlds[128 * 128];   // 32 KB
    int tid = threadIdx.x;
    int row0 = blockIdx.x * 64;

    for (int c = tid; c < 2048; c += 256) {       // W^T, swizzled
        int row = c >> 4, c16 = c & 15;
        uint4 v = *(const uint4*)&WT[row * 128 + c16 * 8];
        *(uint4*)((char*)Wlds + row * 256 + ((c16 * 16) ^ ((row & 7) << 4))) = v;
    }

    int lane = tid & 63, w = tid >> 6;
    int r15 = lane & 15, q = lane >> 4;
    int xo = (r15 & 7) << 4;

    int arow = row0 + 16 * w + r15;
    bool av = arow < NN;
    bfrag_t afr[4];
#pragma unroll
    for (int ks = 0; ks < 4; ++ks) {
        bfrag_t z = {0, 0, 0, 0, 0, 0, 0, 0};
        if (A32 != nullptr) {
            if (av) {
                float4 u = *(const float4*)&A32[(size_t)arow * 128 + ks * 32 + q * 8];
                float4 v = *(const float4*)&A32[(size_t)arow * 128 + ks * 32 + q * 8 + 4];
                uint4 o;
                o.x = pack_bf2(u.x, u.y);
                o.y = pack_bf2(u.z, u.w);
                o.z = pack_bf2(v.x, v.y);
                o.w = pack_bf2(v.z, v.w);
                afr[ks] = *(bfrag_t*)&o;
            } else afr[ks] = z;
        } else {
            afr[ks] = av ? *(const bfrag_t*)&A[(size_t)arow * 128 + ks * 32 + q * 8] : z;
        }
    }
    __syncthreads();

    f4v acc[8];
#pragma unroll
    for (int i = 0; i < 8; ++i) acc[i] = (f4v){0.f, 0.f, 0.f, 0.f};

#pragma unroll
    for (int ks = 0; ks < 4; ++ks) {
        int ko = ks * 64 + q * 16;
#pragma unroll
        for (int nb = 0; nb < 8; ++nb) {
            bfrag_t b = *(const bfrag_t*)((const char*)Wlds + (nb * 16 + r15) * 256 + (ko ^ xo));
            acc[nb] = __builtin_amdgcn_mfma_f32_16x16x32_bf16(afr[ks], b, acc[nb], 0, 0, 0);
        }
    }

#pragma unroll
    for (int reg = 0; reg < 4; ++reg) {
        int gr = row0 + 16 * w + q * 4 + reg;
        if (gr < NN) {
            float sc = dinv[gr];
#pragma unroll
            for (int nb = 0; nb < 8; ++nb)
                m16[(size_t)gr * 128 + nb * 16 + r15] =
                    (unsigned short)f2bf_rne(acc[nb][reg] * sc);
        }
    }
}

// h_out[d][:] = bf16(relu(dinv[d] * sum_{s in N(d)} bf16m[s][:] + b))
// one wave per node; 4 groups of 16 lanes gather full 256 B rows (16 B/lane);
// 16-edge inner step = 4 independent gathers in flight. All __shfl executed
// by ALL lanes (wave-uniform); grp0 writes the full 256 B bf16 output row.
__global__ __launch_bounds__(256) void k_agg(const int* __restrict__ rowptr,
                                             const int* __restrict__ csr,
                                             const uint4* __restrict__ m4,
                                             const float* __restrict__ dinv,
                                             const float* __restrict__ bias,
                                             unsigned short* __restrict__ outb) {
    int w = threadIdx.x >> 6, lane = threadIdx.x & 63;
    int grp = lane >> 4, lj = lane & 15;
    int node = blockIdx.x * 4 + w;
    if (node >= NN) return;
    int beg = rowptr[node], end = rowptr[node + 1];

    float a[8];
#pragma unroll
    for (int q = 0; q < 8; ++q) a[q] = 0.f;

    auto acc8 = [&](uint4 v) {
        a[0] += __uint_as_float(v.x << 16);
        a[1] += __uint_as_float(v.x & 0xffff0000u);
        a[2] += __uint_as_float(v.y << 16);
        a[3] += __uint_as_float(v.y & 0xffff0000u);
        a[4] += __uint_as_float(v.z << 16);
        a[5] += __uint_as_float(v.z & 0xffff0000u);
        a[6] += __uint_as_float(v.w << 16);
        a[7] += __uint_as_float(v.w & 0xffff0000u);
    };

    for (int base = beg; base < end; base += 64) {
        int cnt = min(64, end - base);
        int sv = (lane < cnt) ? csr[base + lane] : 0;
        int k = 0;
        for (; k + 16 <= cnt; k += 16) {
            int s0 = __shfl(sv, k + grp);
            int s1 = __shfl(sv, k + 4 + grp);
            int s2 = __shfl(sv, k + 8 + grp);
            int s3 = __shfl(sv, k + 12 + grp);
            uint4 v0 = m4[(size_t)s0 * 16 + lj];
            uint4 v1 = m4[(size_t)s1 * 16 + lj];
            uint4 v2 = m4[(size_t)s2 * 16 + lj];
            uint4 v3 = m4[(size_t)s3 * 16 + lj];
            acc8(v0); acc8(v1); acc8(v2); acc8(v3);
        }
        for (; k + 4 <= cnt; k += 4) {      // wave-uniform
            int s = __shfl(sv, k + grp);
            uint4 v = m4[(size_t)s * 16 + lj];
            acc8(v);
        }
        int rem = cnt - k;                  // 0..3
        if (rem) {                          // wave-uniform
            int idx = k + grp;
            if (idx >= cnt) idx = cnt - 1;  // clamp; shuffle by ALL lanes
            int s = __shfl(sv, idx);
            if (grp < rem) {                // only accumulate predicated
                uint4 v = m4[(size_t)s * 16 + lj];
                acc8(v);
            }
        }
    }
#pragma unroll
    for (int q = 0; q < 8; ++q) a[q] += __shfl_xor(a[q], 16);
#pragma unroll
    for (int q = 0; q < 8; ++q) a[q] += __shfl_xor(a[q], 32);

    if (grp == 0) {
        float sc = dinv[node];
        float4 b0 = ((const float4*)bias)[lj * 2];
        float4 b1 = ((const float4*)bias)[lj * 2 + 1];
        float r0 = fmaxf(a[0] * sc + b0.x, 0.f);
        float r1 = fmaxf(a[1] * sc + b0.y, 0.f);
        float r2 = fmaxf(a[2] * sc + b0.z, 0.f);
        float r3 = fmaxf(a[3] * sc + b0.w, 0.f);
        float r4 = fmaxf(a[4] * sc + b1.x, 0.f);
        float r5 = fmaxf(a[5] * sc + b1.y, 0.f);
        float r6 = fmaxf(a[6] * sc + b1.z, 0.f);
        float r7 = fmaxf(a[7] * sc + b1.w, 0.f);
        uint4 o;
        o.x = pack_bf2(r0, r1);
        o.y = pack_bf2(r2, r3);
        o.z = pack_bf2(r4, r5);
        o.w = pack_bf2(r6, r7);
        *(uint4*)&outb[(size_t)node * 128 + lj * 8] = o;
    }
}

// ---------------- final: logits = sum_l h_l @ Wjk_l + linb; log_softmax ----------------
__global__ __launch_bounds__(256) void k_jk4(const unsigned short* __restrict__ h0,
                                             const unsigned short* __restrict__ h1,
                                             const unsigned short* __restrict__ h2,
                                             const unsigned short* __restrict__ h3,
                                             const unsigned short* __restrict__ WjT,
                                             const float* __restrict__ linb,
                                             float* __restrict__ out) {
    __shared__ unsigned short Wjlds[4 * 64 * 128];   // 64 KB, swizzled
    int tid = threadIdx.x;
    int row0 = blockIdx.x * 64;

    for (int c = tid; c < 4096; c += 256) {      // 256 rows (l*64+n) x 128
        int row = c >> 4, c16 = c & 15;
        uint4 v = *(const uint4*)&WjT[row * 128 + c16 * 8];
        *(uint4*)((char*)Wjlds + row * 256 + ((c16 * 16) ^ ((row & 7) << 4))) = v;
    }

    int lane = tid & 63, w = tid >> 6;
    int r15 = lane & 15, q = lane >> 4;
    int xo = (r15 & 7) << 4;
    int arow = row0 + 16 * w + r15;
    bool av = arow < NN;
    const unsigned short* hs[4] = {h0, h1, h2, h3};

    __syncthreads();

    f4v accj[4];
#pragma unroll
    for (int i = 0; i < 4; ++i) accj[i] = (f4v){0.f, 0.f, 0.f, 0.f};

#pragma unroll
    for (int l = 0; l < 4; ++l) {
        bfrag_t afr[4];
#pragma unroll
        for (int ks = 0; ks < 4; ++ks) {
            bfrag_t z = {0, 0, 0, 0, 0, 0, 0, 0};
            afr[ks] = av ? *(const bfrag_t*)&hs[l][(size_t)arow * 128 + ks * 32 + q * 8] : z;
        }
#pragma unroll
        for (int ks = 0; ks < 4; ++ks) {
            int ko = ks * 64 + q * 16;
#pragma unroll
            for (int jb = 0; jb < 4; ++jb) {
                bfrag_t b = *(const bfrag_t*)((const char*)Wjlds
                            + (l * 64 + jb * 16 + r15) * 256 + (ko ^ xo));
                accj[jb] = __builtin_amdgcn_mfma_f32_16x16x32_bf16(afr[ks], b, accj[jb], 0, 0, 0);
            }
        }
    }

#pragma unroll
    for (int reg = 0; reg < 4; ++reg) {
        int gr = row0 + 16 * w + q * 4 + reg;    // uniform across the 16-lane group
        float v0 = accj[0][reg] + linb[r15];
        float v1 = accj[1][reg] + linb[16 + r15];
        float v2 = accj[2][reg] + linb[32 + r15];
        float v3 = accj[3][reg] + linb[48 + r15];
        float mx = fmaxf(fmaxf(v0, v1), fmaxf(v2, v3));
#pragma unroll
        for (int s = 1; s < 16; s <<= 1) mx = fmaxf(mx, __shfl_xor(mx, s, 16));
        float sum = expf(v0 - mx) + expf(v1 - mx) + expf(v2 - mx) + expf(v3 - mx);
#pragma unroll
        for (int s = 1; s < 16; s <<= 1) sum += __shfl_xor(sum, s, 16);
        float ls = logf(sum) + mx;
        if (gr < NN) {
            out[(size_t)gr * 64 + r15]      = v0 - ls;
            out[(size_t)gr * 64 + 16 + r15] = v1 - ls;
            out[(size_t)gr * 64 + 32 + r15] = v2 - ls;
            out[(size_t)gr * 64 + 48 + r15] = v3 - ls;
        }
    }
}

// ---------------- launch ----------------

extern "C" void kernel_launch(void* const* d_in, const int* in_sizes, int n_in,
                              void* d_out, int out_size, void* d_ws, size_t ws_size,
                              hipStream_t stream) {
    const float* x    = (const float*)d_in[0];
    const int*   ei   = (const int*)d_in[1];
    const float* W[4] = {(const float*)d_in[2], (const float*)d_in[4],
                         (const float*)d_in[6], (const float*)d_in[8]};
    const float* b[4] = {(const float*)d_in[3], (const float*)d_in[5],
                         (const float*)d_in[7], (const float*)d_in[9]};
    const float* linW = (const float*)d_in[10];
    const float* linb = (const float*)d_in[11];
    float* out = (float*)d_out;

    char* wp = (char*)d_ws;
    auto alloc = [&](size_t bytes) {
        void* p = (void*)wp;
        wp += (bytes + 255) & ~(size_t)255;
        return p;
    };
    int*   flag    = (int*)  alloc(4);
    int*   gcnt    = (int*)  alloc(32);
    int*   deg     = (int*)  alloc((size_t)NN * 4);
    float* dinv    = (float*)alloc((size_t)NN * 4);
    int*   rowptr  = (int*)  alloc((size_t)(NN + 1) * 4);
    int*   bsum    = (int*)  alloc(512);
    int*   boff    = (int*)  alloc(512);
    int*   csr     = (int*)  alloc((size_t)NTOT * 4);
    uint2* binbuf  = (uint2*)alloc((size_t)8 * BCAP * 8);
    int*   rankbuf = (int*)  alloc((size_t)8 * BCAP * 4);
    unsigned short* WT  = (unsigned short*)alloc((size_t)4 * 128 * 128 * 2);
    unsigned short* WjT = (unsigned short*)alloc((size_t)4 * 64 * 128 * 2);
    unsigned short* bufM = (unsigned short*)alloc((size_t)NN * 128 * 2);  // messages
    unsigned short* h[4];
    for (int l = 0; l < 4; ++l)
        h[l] = (unsigned short*)alloc((size_t)NN * 128 * 2);              // bf16 h_l

    dim3 blk(256);
    k_init   <<<391, blk, 0, stream>>>(flag, deg, gcnt);
    k_prep   <<<384, blk, 0, stream>>>(W[0], W[1], W[2], W[3], linW, WT, WjT);
    k_detect <<<1024, blk, 0, stream>>>(ei, flag);
    k_bin    <<<(NE + BCHUNK - 1) / BCHUNK, blk, 0, stream>>>(ei, flag, gcnt, binbuf);
    k_hist8b <<<832, blk, 0, stream>>>(gcnt, binbuf, deg, rankbuf);
    k_scanA  <<<98, blk, 0, stream>>>(deg, rowptr, bsum, dinv);
    k_scanB  <<<1, dim3(128), 0, stream>>>(bsum, boff, rowptr);
    k_scanC  <<<391, blk, 0, stream>>>(rowptr, boff, csr);
    k_scat4  <<<832, blk, 0, stream>>>(gcnt, binbuf, rankbuf, rowptr, csr);

    const unsigned short* lin[4] = {nullptr, h[0], h[1], h[2]};
    for (int l = 0; l < 4; ++l) {
        k_mmf<<<1563, blk, 0, stream>>>(lin[l], l == 0 ? x : nullptr,
                                        WT + (size_t)l * 128 * 128, dinv, bufM);
        k_agg<<<25000, blk, 0, stream>>>(rowptr, csr, (const uint4*)bufM, dinv,
                                         b[l], h[l]);
    }
    k_jk4<<<1563, blk, 0, stream>>>(h[0], h[1], h[2], h[3], WjT, linb, out);
}

// Round 15
// 448.505 us; speedup vs baseline: 1.9310x; 1.1759x over previous
//
#include <hip/hip_runtime.h>
#include <cstdint>
#include <cstddef>

#define NN 100000
#define NE 1600000
#define NTOT (NE + NN)      // 1700000 edges incl self-loops
#define HF 128
#define OF 64
#define SHARD 12500         // NN/8 dst-range per XCD
#define BCHUNK 2048         // edges per k_bin block
#define BCAP 210000         // per-shard bin capacity (mean 200K, +24 sigma)
#define KB 32               // blocks per shard in cnt/fill

typedef short bfrag_t __attribute__((ext_vector_type(8)));   // 8 bf16 = 4 VGPR
typedef float f4v     __attribute__((ext_vector_type(4)));   // MFMA acc

// ---------------- helpers ----------------

__device__ __forceinline__ unsigned int f2bf_rne(float f) {
    unsigned int u = __float_as_uint(f);
    return (u + 0x7fffu + ((u >> 16) & 1u)) >> 16;
}
__device__ __forceinline__ unsigned int pack_bf2(float lo, float hi) {
    return f2bf_rne(lo) | (f2bf_rne(hi) << 16);
}

// ---------------- graph preprocessing ----------------

__global__ __launch_bounds__(64) void k_init(int* gcnt) {
    if (threadIdx.x < 8) gcnt[threadIdx.x] = 0;
}

__device__ __forceinline__ int nt_load(const int* p) {
    return __builtin_nontemporal_load(p);
}

// Single-pass shard binning with per-block int64/int32 self-detection.
// Reads each edge ONCE, LDS-bins by dst shard, writes coalesced (d,s) records
// into 8 per-shard global segments.
__global__ __launch_bounds__(256) void k_bin(const int* __restrict__ ei,
                                             int* __restrict__ gcnt,
                                             uint2* __restrict__ binbuf) {
    __shared__ uint2 bins[8][640];     // 40 KB; 640 cap = +32 sigma vs mean 256
    __shared__ int cnt[8], base[8], anynz;
    int tid = threadIdx.x;
    if (tid < 8) cnt[tid] = 0;
    if (tid == 0) anynz = 0;
    __syncthreads();
    int ebeg = blockIdx.x * BCHUNK;
    int eend = min(NE, ebeg + BCHUNK);
    // per-block dtype detection: odd 32-bit words of int64 data are all zero
    // (node ids < 2^31); int32 data at these positions is random node ids.
    int v = 0;
    for (int e = ebeg + tid; e < eend; e += 256) v |= nt_load(&ei[2 * e + 1]);
    if (v) anynz = 1;                  // benign race: all writers store 1
    __syncthreads();
    bool is64 = (anynz == 0);
    for (int e = ebeg + tid; e < eend; e += 256) {
        int d = is64 ? nt_load(&ei[2 * (NE + e)]) : nt_load(&ei[NE + e]);
        int s = is64 ? nt_load(&ei[2 * e])        : nt_load(&ei[e]);
        int x = (unsigned)d / SHARD;
        int p = atomicAdd(&cnt[x], 1);
        if (p < 640) bins[x][p] = make_uint2((unsigned)d, (unsigned)s);
    }
    __syncthreads();
    if (tid < 8) {
        int c = min(cnt[tid], 640);
        cnt[tid] = c;
        base[tid] = atomicAdd(&gcnt[tid], c);
    }
    __syncthreads();
    for (int x = 0; x < 8; ++x) {
        int c = cnt[x], b0 = base[x];
        for (int i = tid; i < c; i += 256)
            if (b0 + i < BCAP) binbuf[(size_t)x * BCAP + b0 + i] = bins[x][i];
    }
}

// Pass A: per-(shard,block) LDS count-histogram of its record chunk.
// Block b: shard x=b&7 (XCD round-robin), sub-block kb=b>>3 of KB.
__global__ __launch_bounds__(256) void k_cnt(const int* __restrict__ gcnt,
                                             const uint2* __restrict__ binbuf,
                                             int* __restrict__ blockhist) {
    __shared__ int hist[SHARD];        // 50 KB
    int tid = threadIdx.x;
    int x = blockIdx.x & 7, kb = blockIdx.x >> 3;
    int n = min(gcnt[x], BCAP);
    int chunk = (n + KB - 1) / KB;
    int beg = kb * chunk, end = min(n, beg + chunk);
    for (int i = tid; i < SHARD; i += 256) hist[i] = 0;
    __syncthreads();
    for (int i = beg + tid; i < end; i += 256) {
        uint2 r = binbuf[(size_t)x * BCAP + i];
        atomicAdd(&hist[r.x - (unsigned)x * SHARD], 1);
    }
    __syncthreads();
    int* bh = blockhist + ((size_t)x * KB + kb) * SHARD;
    for (int i = tid; i < SHARD; i += 256) bh[i] = hist[i];
}

// Column scan: per node, exclusive-scan the KB per-block counts (in place)
// and write deg = 1 + total (self-loop).
__global__ __launch_bounds__(256) void k_colscan(int* __restrict__ blockhist,
                                                 int* __restrict__ deg) {
    int i = blockIdx.x * 256 + threadIdx.x;
    if (i >= NN) return;
    int x = i / SHARD, ln = i % SHARD;
    int* col = blockhist + (size_t)x * KB * SHARD + ln;
    int s = 0;
#pragma unroll
    for (int kb = 0; kb < KB; ++kb) {
        int c = col[(size_t)kb * SHARD];
        col[(size_t)kb * SHARD] = s;
        s += c;
    }
    deg[i] = 1 + s;
}

// exclusive scan of deg[N] -> rowptr (partial), also dinv = rsqrt(deg)
__global__ __launch_bounds__(256) void k_scanA(const int* deg, int* rowptr, int* bsum,
                                               float* dinv) {
    __shared__ int sh[256];
    int tid = threadIdx.x;
    int base = blockIdx.x * 1024 + tid * 4;
    int v0 = 0, v1 = 0, v2 = 0, v3 = 0;
    if (base + 0 < NN) v0 = deg[base + 0];
    if (base + 1 < NN) v1 = deg[base + 1];
    if (base + 2 < NN) v2 = deg[base + 2];
    if (base + 3 < NN) v3 = deg[base + 3];
    if (base + 0 < NN) dinv[base + 0] = rsqrtf((float)v0);
    if (base + 1 < NN) dinv[base + 1] = rsqrtf((float)v1);
    if (base + 2 < NN) dinv[base + 2] = rsqrtf((float)v2);
    if (base + 3 < NN) dinv[base + 3] = rsqrtf((float)v3);
    int s = v0 + v1 + v2 + v3;
    sh[tid] = s;
    __syncthreads();
    for (int off = 1; off < 256; off <<= 1) {
        int t = (tid >= off) ? sh[tid - off] : 0;
        __syncthreads();
        sh[tid] += t;
        __syncthreads();
    }
    int run = sh[tid] - s;
    if (base + 0 < NN) rowptr[base + 0] = run; run += v0;
    if (base + 1 < NN) rowptr[base + 1] = run; run += v1;
    if (base + 2 < NN) rowptr[base + 2] = run; run += v2;
    if (base + 3 < NN) rowptr[base + 3] = run;
    if (tid == 255) bsum[blockIdx.x] = sh[255];
}

__global__ __launch_bounds__(128) void k_scanB(const int* bsum, int* boff, int* rowptr) {
    __shared__ int sh[128];
    int tid = threadIdx.x;
    int v = (tid < 98) ? bsum[tid] : 0;
    sh[tid] = v;
    __syncthreads();
    for (int off = 1; off < 128; off <<= 1) {
        int t = (tid >= off) ? sh[tid - off] : 0;
        __syncthreads();
        sh[tid] += t;
        __syncthreads();
    }
    if (tid < 98) boff[tid] = sh[tid] - v;
    if (tid == 0) rowptr[NN] = 0;    // real total filled by scanC's last block
}

// finalize rowptr AND place the self-loop in slot 0 of each row
__global__ __launch_bounds__(256) void k_scanC(int* rowptr, const int* boff, int* csr) {
    int i = blockIdx.x * 256 + threadIdx.x;
    if (i < NN) {
        int r = rowptr[i] + boff[i >> 10];
        rowptr[i] = r;
        csr[r] = i;          // self-loop (edge ranks start at 1)
        if (i == NN - 1) { /* rowptr[NN] set below via total */ }
    }
    if (blockIdx.x == 0 && threadIdx.x == 0) rowptr[NN] = NTOT;
}

// Pass B: re-read records, assign local ranks via LDS atomics, write csr.
// csr position = rowptr[d] + 1 + blockhist_offset + local_rank. No global atomics.
__global__ __launch_bounds__(256) void k_fill(const int* __restrict__ gcnt,
                                              const uint2* __restrict__ binbuf,
                                              const int* __restrict__ blockhist,
                                              const int* __restrict__ rowptr,
                                              int* __restrict__ csr) {
    __shared__ int lrank[SHARD];       // 50 KB
    int tid = threadIdx.x;
    int x = blockIdx.x & 7, kb = blockIdx.x >> 3;
    int n = min(gcnt[x], BCAP);
    int chunk = (n + KB - 1) / KB;
    int beg = kb * chunk, end = min(n, beg + chunk);
    for (int i = tid; i < SHARD; i += 256) lrank[i] = 0;
    __syncthreads();
    const int* bh = blockhist + ((size_t)x * KB + kb) * SHARD;
    for (int i = beg + tid; i < end; i += 256) {
        uint2 r = binbuf[(size_t)x * BCAP + i];
        int ln = r.x - (unsigned)x * SHARD;
        int lr = atomicAdd(&lrank[ln], 1);
        csr[rowptr[r.x] + 1 + bh[ln] + lr] = (int)r.y;
    }
}

// ---------------- weight prep: bf16 + transpose to [n][k] ----------------
__global__ __launch_bounds__(256) void k_prep(const float* __restrict__ W0,
                                              const float* __restrict__ W1,
                                              const float* __restrict__ W2,
                                              const float* __restrict__ W3,
                                              const float* __restrict__ linW,
                                              unsigned short* __restrict__ WT,
                                              unsigned short* __restrict__ WjT) {
    int idx = blockIdx.x * 256 + threadIdx.x;
    if (idx < 4 * 128 * 128) {
        int l = idx >> 14, r = idx & 16383, n = r >> 7, k = r & 127;
        const float* Wl = (l == 0) ? W0 : (l == 1) ? W1 : (l == 2) ? W2 : W3;
        WT[idx] = (unsigned short)f2bf_rne(Wl[k * 128 + n]);
    } else if (idx < 4 * 128 * 128 + 4 * 64 * 128) {
        int i2 = idx - 65536;
        int l = i2 >> 13, r = i2 & 8191, n = r >> 7, k = r & 127;
        WjT[i2] = (unsigned short)f2bf_rne(linW[(size_t)(l * 128 + k) * 64 + n]);
    }
}

// ---------------- MFMA matmul: m = bf16(dinv * (A @ W)) ----------------
__global__ __launch_bounds__(256) void k_mmf(const unsigned short* __restrict__ A,
                                             const float* __restrict__ A32,
                                             const unsigned short* __restrict__ WT,
                                             const float* __restrict__ dinv,
                                             unsigned short* __restrict__ m16) {
    __shared__ unsigned short Wlds[128 * 128];   // 32 KB
    int tid = threadIdx.x;
    int row0 = blockIdx.x * 64;

    for (int c = tid; c < 2048; c += 256) {       // W^T, swizzled
        int row = c >> 4, c16 = c & 15;
        uint4 v = *(const uint4*)&WT[row * 128 + c16 * 8];
        *(uint4*)((char*)Wlds + row * 256 + ((c16 * 16) ^ ((row & 7) << 4))) = v;
    }

    int lane = tid & 63, w = tid >> 6;
    int r15 = lane & 15, q = lane >> 4;
    int xo = (r15 & 7) << 4;

    int arow = row0 + 16 * w + r15;
    bool av = arow < NN;
    bfrag_t afr[4];
#pragma unroll
    for (int ks = 0; ks < 4; ++ks) {
        bfrag_t z = {0, 0, 0, 0, 0, 0, 0, 0};
        if (A32 != nullptr) {
            if (av) {
                float4 u = *(const float4*)&A32[(size_t)arow * 128 + ks * 32 + q * 8];
                float4 v = *(const float4*)&A32[(size_t)arow * 128 + ks * 32 + q * 8 + 4];
                uint4 o;
                o.x = pack_bf2(u.x, u.y);
                o.y = pack_bf2(u.z, u.w);
                o.z = pack_bf2(v.x, v.y);
                o.w = pack_bf2(v.z, v.w);
                afr[ks] = *(bfrag_t*)&o;
            } else afr[ks] = z;
        } else {
            afr[ks] = av ? *(const bfrag_t*)&A[(size_t)arow * 128 + ks * 32 + q * 8] : z;
        }
    }
    __syncthreads();

    f4v acc[8];
#pragma unroll
    for (int i = 0; i < 8; ++i) acc[i] = (f4v){0.f, 0.f, 0.f, 0.f};

#pragma unroll
    for (int ks = 0; ks < 4; ++ks) {
        int ko = ks * 64 + q * 16;
#pragma unroll
        for (int nb = 0; nb < 8; ++nb) {
            bfrag_t b = *(const bfrag_t*)((const char*)Wlds + (nb * 16 + r15) * 256 + (ko ^ xo));
            acc[nb] = __builtin_amdgcn_mfma_f32_16x16x32_bf16(afr[ks], b, acc[nb], 0, 0, 0);
        }
    }

#pragma unroll
    for (int reg = 0; reg < 4; ++reg) {
        int gr = row0 + 16 * w + q * 4 + reg;
        if (gr < NN) {
            float sc = dinv[gr];
#pragma unroll
            for (int nb = 0; nb < 8; ++nb)
                m16[(size_t)gr * 128 + nb * 16 + r15] =
                    (unsigned short)f2bf_rne(acc[nb][reg] * sc);
        }
    }
}

// h_out[d][:] = bf16(relu(dinv[d] * sum_{s in N(d)} bf16m[s][:] + b))
__global__ __launch_bounds__(256) void k_agg(const int* __restrict__ rowptr,
                                             const int* __restrict__ csr,
                                             const uint4* __restrict__ m4,
                                             const float* __restrict__ dinv,
                                             const float* __restrict__ bias,
                                             unsigned short* __restrict__ outb) {
    int w = threadIdx.x >> 6, lane = threadIdx.x & 63;
    int grp = lane >> 4, lj = lane & 15;
    int node = blockIdx.x * 4 + w;
    if (node >= NN) return;
    int beg = rowptr[node], end = rowptr[node + 1];

    float a[8];
#pragma unroll
    for (int q = 0; q < 8; ++q) a[q] = 0.f;

    auto acc8 = [&](uint4 v) {
        a[0] += __uint_as_float(v.x << 16);
        a[1] += __uint_as_float(v.x & 0xffff0000u);
        a[2] += __uint_as_float(v.y << 16);
        a[3] += __uint_as_float(v.y & 0xffff0000u);
        a[4] += __uint_as_float(v.z << 16);
        a[5] += __uint_as_float(v.z & 0xffff0000u);
        a[6] += __uint_as_float(v.w << 16);
        a[7] += __uint_as_float(v.w & 0xffff0000u);
    };

    for (int base = beg; base < end; base += 64) {
        int cnt = min(64, end - base);
        int sv = (lane < cnt) ? csr[base + lane] : 0;
        int k = 0;
        for (; k + 16 <= cnt; k += 16) {
            int s0 = __shfl(sv, k + grp);
            int s1 = __shfl(sv, k + 4 + grp);
            int s2 = __shfl(sv, k + 8 + grp);
            int s3 = __shfl(sv, k + 12 + grp);
            uint4 v0 = m4[(size_t)s0 * 16 + lj];
            uint4 v1 = m4[(size_t)s1 * 16 + lj];
            uint4 v2 = m4[(size_t)s2 * 16 + lj];
            uint4 v3 = m4[(size_t)s3 * 16 + lj];
            acc8(v0); acc8(v1); acc8(v2); acc8(v3);
        }
        for (; k + 4 <= cnt; k += 4) {      // wave-uniform
            int s = __shfl(sv, k + grp);
            uint4 v = m4[(size_t)s * 16 + lj];
            acc8(v);
        }
        int rem = cnt - k;                  // 0..3
        if (rem) {                          // wave-uniform
            int idx = k + grp;
            if (idx >= cnt) idx = cnt - 1;  // clamp; shuffle by ALL lanes
            int s = __shfl(sv, idx);
            if (grp < rem) {                // only accumulate predicated
                uint4 v = m4[(size_t)s * 16 + lj];
                acc8(v);
            }
        }
    }
#pragma unroll
    for (int q = 0; q < 8; ++q) a[q] += __shfl_xor(a[q], 16);
#pragma unroll
    for (int q = 0; q < 8; ++q) a[q] += __shfl_xor(a[q], 32);

    if (grp == 0) {
        float sc = dinv[node];
        float4 b0 = ((const float4*)bias)[lj * 2];
        float4 b1 = ((const float4*)bias)[lj * 2 + 1];
        float r0 = fmaxf(a[0] * sc + b0.x, 0.f);
        float r1 = fmaxf(a[1] * sc + b0.y, 0.f);
        float r2 = fmaxf(a[2] * sc + b0.z, 0.f);
        float r3 = fmaxf(a[3] * sc + b0.w, 0.f);
        float r4 = fmaxf(a[4] * sc + b1.x, 0.f);
        float r5 = fmaxf(a[5] * sc + b1.y, 0.f);
        float r6 = fmaxf(a[6] * sc + b1.z, 0.f);
        float r7 = fmaxf(a[7] * sc + b1.w, 0.f);
        uint4 o;
        o.x = pack_bf2(r0, r1);
        o.y = pack_bf2(r2, r3);
        o.z = pack_bf2(r4, r5);
        o.w = pack_bf2(r6, r7);
        *(uint4*)&outb[(size_t)node * 128 + lj * 8] = o;
    }
}

// ---------------- final: logits = sum_l h_l @ Wjk_l + linb; log_softmax ----------------
__global__ __launch_bounds__(256) void k_jk4(const unsigned short* __restrict__ h0,
                                             const unsigned short* __restrict__ h1,
                                             const unsigned short* __restrict__ h2,
                                             const unsigned short* __restrict__ h3,
                                             const unsigned short* __restrict__ WjT,
                                             const float* __restrict__ linb,
                                             float* __restrict__ out) {
    __shared__ unsigned short Wjlds[4 * 64 * 128];   // 64 KB, swizzled
    int tid = threadIdx.x;
    int row0 = blockIdx.x * 64;

    for (int c = tid; c < 4096; c += 256) {      // 256 rows (l*64+n) x 128
        int row = c >> 4, c16 = c & 15;
        uint4 v = *(const uint4*)&WjT[row * 128 + c16 * 8];
        *(uint4*)((char*)Wjlds + row * 256 + ((c16 * 16) ^ ((row & 7) << 4))) = v;
    }

    int lane = tid & 63, w = tid >> 6;
    int r15 = lane & 15, q = lane >> 4;
    int xo = (r15 & 7) << 4;
    int arow = row0 + 16 * w + r15;
    bool av = arow < NN;
    const unsigned short* hs[4] = {h0, h1, h2, h3};

    __syncthreads();

    f4v accj[4];
#pragma unroll
    for (int i = 0; i < 4; ++i) accj[i] = (f4v){0.f, 0.f, 0.f, 0.f};

#pragma unroll
    for (int l = 0; l < 4; ++l) {
        bfrag_t afr[4];
#pragma unroll
        for (int ks = 0; ks < 4; ++ks) {
            bfrag_t z = {0, 0, 0, 0, 0, 0, 0, 0};
            afr[ks] = av ? *(const bfrag_t*)&hs[l][(size_t)arow * 128 + ks * 32 + q * 8] : z;
        }
#pragma unroll
        for (int ks = 0; ks < 4; ++ks) {
            int ko = ks * 64 + q * 16;
#pragma unroll
            for (int jb = 0; jb < 4; ++jb) {
                bfrag_t b = *(const bfrag_t*)((const char*)Wjlds
                            + (l * 64 + jb * 16 + r15) * 256 + (ko ^ xo));
                accj[jb] = __builtin_amdgcn_mfma_f32_16x16x32_bf16(afr[ks], b, accj[jb], 0, 0, 0);
            }
        }
    }

#pragma unroll
    for (int reg = 0; reg < 4; ++reg) {
        int gr = row0 + 16 * w + q * 4 + reg;    // uniform across the 16-lane group
        float v0 = accj[0][reg] + linb[r15];
        float v1 = accj[1][reg] + linb[16 + r15];
        float v2 = accj[2][reg] + linb[32 + r15];
        float v3 = accj[3][reg] + linb[48 + r15];
        float mx = fmaxf(fmaxf(v0, v1), fmaxf(v2, v3));
#pragma unroll
        for (int s = 1; s < 16; s <<= 1) mx = fmaxf(mx, __shfl_xor(mx, s, 16));
        float sum = expf(v0 - mx) + expf(v1 - mx) + expf(v2 - mx) + expf(v3 - mx);
#pragma unroll
        for (int s = 1; s < 16; s <<= 1) sum += __shfl_xor(sum, s, 16);
        float ls = logf(sum) + mx;
        if (gr < NN) {
            out[(size_t)gr * 64 + r15]      = v0 - ls;
            out[(size_t)gr * 64 + 16 + r15] = v1 - ls;
            out[(size_t)gr * 64 + 32 + r15] = v2 - ls;
            out[(size_t)gr * 64 + 48 + r15] = v3 - ls;
        }
    }
}

// ---------------- launch ----------------

extern "C" void kernel_launch(void* const* d_in, const int* in_sizes, int n_in,
                              void* d_out, int out_size, void* d_ws, size_t ws_size,
                              hipStream_t stream) {
    const float* x    = (const float*)d_in[0];
    const int*   ei   = (const int*)d_in[1];
    const float* W[4] = {(const float*)d_in[2], (const float*)d_in[4],
                         (const float*)d_in[6], (const float*)d_in[8]};
    const float* b[4] = {(const float*)d_in[3], (const float*)d_in[5],
                         (const float*)d_in[7], (const float*)d_in[9]};
    const float* linW = (const float*)d_in[10];
    const float* linb = (const float*)d_in[11];
    float* out = (float*)d_out;

    char* wp = (char*)d_ws;
    auto alloc = [&](size_t bytes) {
        void* p = (void*)wp;
        wp += (bytes + 255) & ~(size_t)255;
        return p;
    };
    int*   gcnt    = (int*)  alloc(32);
    int*   deg     = (int*)  alloc((size_t)NN * 4);
    float* dinv    = (float*)alloc((size_t)NN * 4);
    int*   rowptr  = (int*)  alloc((size_t)(NN + 1) * 4);
    int*   bsum    = (int*)  alloc(512);
    int*   boff    = (int*)  alloc(512);
    int*   csr     = (int*)  alloc((size_t)NTOT * 4);
    uint2* binbuf  = (uint2*)alloc((size_t)8 * BCAP * 8);
    int*   blockhist = (int*)alloc((size_t)8 * KB * SHARD * 4);   // 12.8 MB
    unsigned short* WT  = (unsigned short*)alloc((size_t)4 * 128 * 128 * 2);
    unsigned short* WjT = (unsigned short*)alloc((size_t)4 * 64 * 128 * 2);
    unsigned short* bufM = (unsigned short*)alloc((size_t)NN * 128 * 2);  // messages
    unsigned short* h[4];
    for (int l = 0; l < 4; ++l)
        h[l] = (unsigned short*)alloc((size_t)NN * 128 * 2);              // bf16 h_l

    dim3 blk(256);
    k_init   <<<1, dim3(64), 0, stream>>>(gcnt);
    k_prep   <<<384, blk, 0, stream>>>(W[0], W[1], W[2], W[3], linW, WT, WjT);
    k_bin    <<<(NE + BCHUNK - 1) / BCHUNK, blk, 0, stream>>>(ei, gcnt, binbuf);
    k_cnt    <<<8 * KB, blk, 0, stream>>>(gcnt, binbuf, blockhist);
    k_colscan<<<391, blk, 0, stream>>>(blockhist, deg);
    k_scanA  <<<98, blk, 0, stream>>>(deg, rowptr, bsum, dinv);
    k_scanB  <<<1, dim3(128), 0, stream>>>(bsum, boff, rowptr);
    k_scanC  <<<391, blk, 0, stream>>>(rowptr, boff, csr);
    k_fill   <<<8 * KB, blk, 0, stream>>>(gcnt, binbuf, blockhist, rowptr, csr);

    const unsigned short* lin[4] = {nullptr, h[0], h[1], h[2]};
    for (int l = 0; l < 4; ++l) {
        k_mmf<<<1563, blk, 0, stream>>>(lin[l], l == 0 ? x : nullptr,
                                        WT + (size_t)l * 128 * 128, dinv, bufM);
        k_agg<<<25000, blk, 0, stream>>>(rowptr, csr, (const uint4*)bufM, dinv,
                                         b[l], h[l]);
    }
    k_jk4<<<1563, blk, 0, stream>>>(h[0], h[1], h[2], h[3], WjT, linb, out);
}